// Round 11
// baseline (343.055 us; speedup 1.0000x reference)
//
#include <hip/hip_runtime.h>
#include <cfloat>
#include <cstdint>

#define NB 32
#define NP 1024
#define NK 20
#define NPTS 32768  // NB*NP

typedef __attribute__((ext_vector_type(8))) short bf16x8;
typedef __attribute__((ext_vector_type(4))) float f32x4;

__device__ __forceinline__ unsigned bf16rne(float v) {
  const unsigned u = __float_as_uint(v);
  return (u + 0x7fffu + ((u >> 16) & 1u)) >> 16;
}

// inverse of the sortable transform u ^= (int(u)>>31 | 0x80000000)
__device__ __forceinline__ float unsort_f(unsigned s) {
  const unsigned m = (~(unsigned)((int)s >> 31)) | 0x80000000u;
  return __uint_as_float(s ^ m);
}

// ---------------------------------------------------------------------------
// d2[p] = sum x^2 (fp32 exact).
// ---------------------------------------------------------------------------
__global__ __launch_bounds__(256) void kd2(const float* __restrict__ x, int dim,
                                           float* __restrict__ d2) {
  int p = blockIdx.x * 256 + threadIdx.x;
  if (p >= NPTS) return;
  if (dim == 64) {
    const float4* xr = (const float4*)(x + (size_t)p * 64);
    float s = 0.f;
#pragma unroll
    for (int dq = 0; dq < 16; dq++) {
      float4 v = xr[dq];
      s = fmaf(v.x, v.x, s);
      s = fmaf(v.y, v.y, s);
      s = fmaf(v.z, v.z, s);
      s = fmaf(v.w, v.w, s);
    }
    d2[p] = s;
  } else {
    float s = 0.f;
#pragma unroll
    for (int d = 0; d < 3; d++) {
      float v = x[p * 3 + d];
      s = fmaf(v, v, s);
    }
    d2[p] = s;
  }
}

// ---------------------------------------------------------------------------
// kxprep: convert x1 into MFMA fragment order, bf16 hi/lo (HW-validated).
// ---------------------------------------------------------------------------
__global__ __launch_bounds__(256) void kxprep(const float* __restrict__ x,
                                              unsigned short* __restrict__ Xh,
                                              unsigned short* __restrict__ Xl) {
  const int t = blockIdx.x * 256 + threadIdx.x;  // 262144
  const int p = t >> 3, g = t & 7;               // k = g*8 + j
  const float4* xr = (const float4*)(x + (size_t)p * 64 + g * 8);
  const float4 v0 = xr[0];
  const float4 v1 = xr[1];
  const float vv[8] = {v0.x, v0.y, v0.z, v0.w, v1.x, v1.y, v1.z, v1.w};
  unsigned short h[8], l[8];
#pragma unroll
  for (int j = 0; j < 8; j++) {
    const float z = vv[j];
    const unsigned u = __float_as_uint(z);
    const unsigned hb = (u + 0x7fffu + ((u >> 16) & 1u)) & 0xffff0000u;
    h[j] = (unsigned short)(hb >> 16);
    l[j] = (unsigned short)bf16rne(z - __uint_as_float(hb));
  }
  const int off = (((p >> 4) * 2 + (g >> 2)) * 64 + ((g & 3) << 4) + (p & 15)) * 8;
  *(uint4*)&Xh[off] = *(const uint4*)&h[0];
  *(uint4*)&Xl[off] = *(const uint4*)&l[0];
}

// ---------------------------------------------------------------------------
// select20k (R25): exact top-20 SET on pre-transformed sortable u32 keys.
// Stage 1: interp-search pivot with cnt in [20,64] (ballot->s_bcnt1 counts).
// Stage 2: compact candidates (<=64) to one per lane in LDS + rank pass
// (R24-verified). Fallback (value plateau, rare): u64 bisect on the fly.
// Key order ii = i*4+j <-> element q = i*256 + lane*4 + j (tie-break =
// lax.top_k, low 10 idx bits).
// ---------------------------------------------------------------------------
__device__ __forceinline__ void select20k(const unsigned* k32, unsigned long long* w,
                                          int lane, int pg, int gbase,
                                          int* __restrict__ idxo) {
  // lane-local min; butterfly: global min (mn) and max-of-lane-mins (mlm).
  unsigned lmn = k32[0];
#pragma unroll
  for (int ii = 1; ii < 16; ii++) lmn = k32[ii] < lmn ? k32[ii] : lmn;
  unsigned mn = lmn, mlm = lmn;
#pragma unroll
  for (int s = 1; s < 64; s <<= 1) {
    const unsigned a = __shfl_xor(mn, s, 64);
    const unsigned b = __shfl_xor(mlm, s, 64);
    mn = a < mn ? a : mn;
    mlm = b > mlm ? b : mlm;
  }
  // Stage 1. Invariants: cnt(<lo32) < 20, cnt(<hi32) > 64.
  unsigned lo32 = mn;                                      // cnt == 0
  unsigned long long hi32 = (unsigned long long)mlm + 1;   // cnt(<hi32) >= 64
  float flo = unsort_f(mn), fhi = unsort_f(mlm);
  float clo = 0.f, chi = 140.f;  // count estimates at flo/fhi (chi is a guess)
  unsigned m32 = 0;
  bool found = false;
  for (int it = 0; it < 40; ++it) {
    if (hi32 - (unsigned long long)lo32 <= 1) break;  // plateau -> fallback
    unsigned m;
    if (it < 6) {
      float fr = (42.f - clo) / (chi - clo);
      fr = fr < 0.04f ? 0.04f : (fr > 0.96f ? 0.96f : fr);
      const float pf = fmaf(fhi - flo, fr, flo);
      unsigned u = __float_as_uint(pf);
      u ^= (((int)u >> 31) | 0x80000000u);
      m = u;
      if (m <= lo32) m = lo32 + 1;                       // strict interior
      if ((unsigned long long)m >= hi32) m = (unsigned)(hi32 - 1);
    } else {
      m = (unsigned)(lo32 + ((hi32 - lo32) >> 1));
    }
    int cnt = 0;
#pragma unroll
    for (int ii = 0; ii < 16; ii++) cnt += __popcll(__ballot(k32[ii] < m));
    if (cnt < 20) {
      lo32 = m;
      flo = unsort_f(m);
      clo = (float)cnt;
    } else if (cnt > 64) {
      hi32 = m;
      fhi = unsort_f(m);
      chi = (float)cnt;
    } else {
      m32 = m;
      found = true;
      break;
    }
  }

  if (found) {
    // candidates: k32 < m32, total in [20,64] -> compact to one per lane.
    unsigned mask = 0;
#pragma unroll
    for (int ii = 0; ii < 16; ii++) mask |= (k32[ii] < m32) ? (1u << ii) : 0u;
    const int lc = __popc(mask);
    int x = lc;
#pragma unroll
    for (int s = 1; s < 64; s <<= 1) {
      const int y = __shfl_up(x, s, 64);
      if (lane >= s) x += y;
    }
    int off = x - lc;  // exclusive prefix; total <= 64 so off stays < 64
    w[lane] = ~0ULL;
    __builtin_amdgcn_wave_barrier();
#pragma unroll
    for (int i = 0; i < 4; i++)
#pragma unroll
      for (int j = 0; j < 4; j++) {
        const int ii = i * 4 + j;
        if ((mask & (1u << ii)) && off < 64) {
          w[off] = ((unsigned long long)k32[ii] << 10) |
                   (unsigned)(i * 256 + (lane << 2) + j);
          off++;
        }
      }
    __builtin_amdgcn_wave_barrier();
    const unsigned long long K = w[lane];  // pad lanes hold ~0ULL
    // Rank pass (R24-verified): 64 broadcast LDS reads, fully pipelined.
    int rank = 0;
#pragma unroll
    for (int m = 0; m < 64; m++) rank += (K > w[m]) ? 1 : 0;
    if (K != ~0ULL && rank < NK)
      idxo[(size_t)pg * NK + rank] = gbase + (int)(K & 1023u);
  } else {
    // plateau fallback: bisect full u64 keys (distinct -> exact cnt==20
    // reachable), keys rebuilt on the fly to keep VGPR pressure low.
    unsigned long long lo64 = ((unsigned long long)lo32) << 10;  // cnt < 20
    unsigned long long hi64 = hi32 << 10;                        // cnt > 64
    unsigned long long cut = hi64;
    for (int it = 0; it < 48 && (hi64 - lo64) > 1; ++it) {
      const unsigned long long m = lo64 + ((hi64 - lo64) >> 1);
      int cnt = 0;
#pragma unroll
      for (int ii = 0; ii < 16; ii++) {
        const unsigned long long key =
            ((unsigned long long)k32[ii] << 10) |
            (unsigned)(((ii >> 2) << 8) + (lane << 2) + (ii & 3));
        cnt += __popcll(__ballot(key < m));
      }
      if (cnt == 20) {
        cut = m;
        break;
      }
      if (cnt < 20)
        lo64 = m;
      else
        hi64 = m;
      cut = hi64;
    }
    int base = 0;
#pragma unroll
    for (int ii = 0; ii < 16; ii++) {
      const unsigned long long key =
          ((unsigned long long)k32[ii] << 10) |
          (unsigned)(((ii >> 2) << 8) + (lane << 2) + (ii & 3));
      const unsigned long long b = __ballot(key < cut);
      if (key < cut) {
        const int slot = base + __builtin_amdgcn_mbcnt_hi(
                                    (unsigned)(b >> 32),
                                    __builtin_amdgcn_mbcnt_lo((unsigned)b, 0));
        idxo[(size_t)pg * NK + slot] = gbase + (int)(key & 1023u);
      }
      base += __popcll(b);
    }
  }
}

// float-input wrapper (kfsel1 path): transform then select on keys.
__device__ __forceinline__ void select20(const float* dv, unsigned long long* w,
                                         int lane, int pg, int gbase,
                                         int* __restrict__ idxo) {
  unsigned k32[16];
#pragma unroll
  for (int ii = 0; ii < 16; ii++) {
    unsigned u = __float_as_uint(dv[ii]);
    u ^= (((int)u >> 31) | 0x80000000u);  // sortable transform
    k32[ii] = u;
  }
  select20k(k32, w, lane, pg, gbase, idxo);
}

// ---------------------------------------------------------------------------
// kfsel1 v2: fused dim=3 distance + top-20 select, one point per wave.
// ---------------------------------------------------------------------------
__global__ __launch_bounds__(512) void kfsel1(const float* __restrict__ pos,
                                              const float* __restrict__ d2,
                                              int* __restrict__ idxo) {
  __shared__ float px[1024], py[1024], pz[1024], pd2[1024];
  __shared__ unsigned long long lw[8][64];
  const int tid = threadIdx.x;
  const int lane = tid & 63;
  const int w = tid >> 6;
  const int cloud = blockIdx.x >> 7;  // 128 blocks per cloud
  const int mb = blockIdx.x & 127;
  const int cb = cloud << 10;

  if (tid < 256) {  // stage cloud: thread t -> points 4t..4t+3, SoA transpose
    const float4* ppos = (const float4*)(pos + (size_t)cb * 3 + tid * 12);
    const float4 a = ppos[0], b = ppos[1], c = ppos[2];
    *(float4*)&px[tid * 4] = make_float4(a.x, a.w, b.z, c.y);
    *(float4*)&py[tid * 4] = make_float4(a.y, b.x, b.w, c.z);
    *(float4*)&pz[tid * 4] = make_float4(a.z, b.y, c.x, c.w);
  }
  *(float2*)&pd2[tid * 2] = *(const float2*)(d2 + cb + tid * 2);
  __syncthreads();

  const int pl = mb * 8 + w;  // this wave's point (wave-uniform)
  const float xi0 = px[pl], xi1 = py[pl], xi2 = pz[pl];
  const float dp = pd2[pl];
  float dv[16];
#pragma unroll
  for (int i = 0; i < 4; i++) {  // q = i*256 + lane*4 + j (select20 mapping)
    const float4 X = *(const float4*)&px[i * 256 + lane * 4];
    const float4 Y = *(const float4*)&py[i * 256 + lane * 4];
    const float4 Z = *(const float4*)&pz[i * 256 + lane * 4];
    const float4 Q = *(const float4*)&pd2[i * 256 + lane * 4];
    const float xs[4] = {X.x, X.y, X.z, X.w};
    const float ys[4] = {Y.x, Y.y, Y.z, Y.w};
    const float zs[4] = {Z.x, Z.y, Z.z, Z.w};
    const float qs[4] = {Q.x, Q.y, Q.z, Q.w};
#pragma unroll
    for (int j = 0; j < 4; j++) {
      float acc = 0.f;
      acc = fmaf(xi0, xs[j], acc);
      acc = fmaf(xi1, ys[j], acc);
      acc = fmaf(xi2, zs[j], acc);
      dv[i * 4 + j] = fmaf(-2.f, acc, dp + qs[j]);
    }
  }
  select20(dv, lw[w], lane, cb + pl, cb, idxo);
}

// ---------------------------------------------------------------------------
// kdsel2 v3 (R25): fused layer-2 kNN, HALF-STRIP double-pass for occupancy.
// v1 diagnosis: 68KB LDS -> 2 blocks/CU (16-wave cap), measured 34% occ,
// VALU-bound select starved. v3: same 16-row x 1024-col strip per block,
// computed in two 512-col halves through ONE 32KB buffer. Phase 1a (cols
// 0..511, wave w owns 4 tiles) -> barrier -> extract half-0 keys (sortable
// transform applied at extraction; exact bijection) -> barrier -> phase 1b
// (cols 512..1023) -> barrier -> selects read half-1 lazily (strip intact).
// Same MFMA chain, swizzle, select -> bit-identical neighbor sets. LDS
// 36KB -> 4 blocks/CU; launch_bounds(512,8) pins VGPR<=64 for 32 waves/CU.
// ---------------------------------------------------------------------------
__global__ __launch_bounds__(512, 8) void kdsel2(const unsigned short* __restrict__ Xh,
                                                 const unsigned short* __restrict__ Xl,
                                                 const float* __restrict__ d2,
                                                 int* __restrict__ idxo) {
  __shared__ __align__(16) float Dl[16][512];
  __shared__ unsigned long long lw[8][64];
  const int lane = threadIdx.x & 63;
  const int w = threadIdx.x >> 6;
  const int cloud = blockIdx.x & 31;  // XCD-local cloud assignment
  const int rb = blockIdx.x >> 5;     // 0..63 row-block within cloud
  const int cb = cloud * 1024;
  const int rowb = rb * 16;           // local row base

  // A fragments for the block's 16 rows (wave-duplicated; L2 broadcast)
  bf16x8 Ah[2], Al[2];
#pragma unroll
  for (int ks = 0; ks < 2; ks++) {
    const int tg = (cb + rowb) >> 4;
    const size_t base = ((size_t)(tg * 2 + ks) * 64 + lane) * 8;
    Ah[ks] = *(const bf16x8*)&Xh[base];
    Al[ks] = *(const bf16x8*)&Xl[base];
  }
  float d2r[4];
#pragma unroll
  for (int r = 0; r < 4; r++) d2r[r] = d2[cb + rowb + (lane >> 4) * 4 + r];

  unsigned kk0[2][8];  // half-0 keys for this wave's 2 points

  for (int h = 0; h < 2; h++) {
    // distance half-strip: wave w owns 4 tiles (64 cols of this half)
#pragma unroll
    for (int nt = 0; nt < 4; nt++) {
      const int c0 = w * 64 + nt * 16;   // local col within half
      const int cg = cb + h * 512 + c0;  // global col
      bf16x8 Bh2[2], Bl2[2];
#pragma unroll
      for (int ks = 0; ks < 2; ks++) {
        const int tg = cg >> 4;
        const size_t base = ((size_t)(tg * 2 + ks) * 64 + lane) * 8;
        Bh2[ks] = *(const bf16x8*)&Xh[base];
        Bl2[ks] = *(const bf16x8*)&Xl[base];
      }
      const float d2c = d2[cg + (lane & 15)];
      f32x4 C = {0.f, 0.f, 0.f, 0.f};
      C = __builtin_amdgcn_mfma_f32_16x16x32_bf16(Ah[0], Bh2[0], C, 0, 0, 0);
      C = __builtin_amdgcn_mfma_f32_16x16x32_bf16(Ah[0], Bl2[0], C, 0, 0, 0);
      C = __builtin_amdgcn_mfma_f32_16x16x32_bf16(Al[0], Bh2[0], C, 0, 0, 0);
      C = __builtin_amdgcn_mfma_f32_16x16x32_bf16(Ah[1], Bh2[1], C, 0, 0, 0);
      C = __builtin_amdgcn_mfma_f32_16x16x32_bf16(Ah[1], Bl2[1], C, 0, 0, 0);
      C = __builtin_amdgcn_mfma_f32_16x16x32_bf16(Al[1], Bh2[1], C, 0, 0, 0);
#pragma unroll
      for (int r = 0; r < 4; r++) {
        const int row = (lane >> 4) * 4 + r;
        const int col = c0 + (lane & 15);
        Dl[row][col ^ ((row & 7) << 2)] = fmaf(-2.f, C[r], d2r[r] + d2c);
      }
    }
    __syncthreads();
    if (h == 0) {
      // extract half-0 keys for BOTH points before the strip is overwritten
#pragma unroll
      for (int pp = 0; pp < 2; pp++) {
        const int pl = w * 2 + pp;
        const int s = (pl & 7) << 2;
#pragma unroll
        for (int i2 = 0; i2 < 2; i2++) {
          const float4 d4 = *(const float4*)&Dl[pl][(i2 * 256 + lane * 4) ^ s];
          const float dvv[4] = {d4.x, d4.y, d4.z, d4.w};
#pragma unroll
          for (int j = 0; j < 4; j++) {
            unsigned u = __float_as_uint(dvv[j]);
            u ^= (((int)u >> 31) | 0x80000000u);
            kk0[pp][i2 * 4 + j] = u;
          }
        }
      }
      __syncthreads();
    }
  }

  // strip holds half-1 and stays intact through both selects.
  for (int pp = 0; pp < 2; pp++) {
    const int pl = w * 2 + pp;  // local point 0..15 (wave-uniform)
    const int s = (pl & 7) << 2;
    unsigned k32[16];
#pragma unroll
    for (int ii = 0; ii < 8; ii++) k32[ii] = kk0[pp][ii];
#pragma unroll
    for (int i2 = 0; i2 < 2; i2++) {
      const float4 d4 = *(const float4*)&Dl[pl][(i2 * 256 + lane * 4) ^ s];
      const float dvv[4] = {d4.x, d4.y, d4.z, d4.w};
#pragma unroll
      for (int j = 0; j < 4; j++) {
        unsigned u = __float_as_uint(dvv[j]);
        u ^= (((int)u >> 31) | 0x80000000u);
        k32[8 + i2 * 4 + j] = u;
      }
    }
    select20k(k32, lw[w], lane, cb + rowb + pl, cb, idxo);
  }
}

// ---------------------------------------------------------------------------
// Edge moments, atomic-free.
// ---------------------------------------------------------------------------
__global__ __launch_bounds__(256) void kstats(const float* __restrict__ pos,
                                              const int* __restrict__ idx,
                                              double* __restrict__ Spart) {
  __shared__ float red[4][42];
  const int tid = threadIdx.x;
  const int w = tid >> 6;
  int p = blockIdx.x * 256 + tid;
  float xi0 = pos[p * 3], xi1 = pos[p * 3 + 1], xi2 = pos[p * 3 + 2];
  float s1[6];
  float s2[36];
#pragma unroll
  for (int a = 0; a < 6; a++) s1[a] = 0.f;
#pragma unroll
  for (int a = 0; a < 36; a++) s2[a] = 0.f;
  for (int k = 0; k < NK; k++) {
    int j = idx[p * NK + k];
    float e[6];
    e[0] = xi0;
    e[1] = xi1;
    e[2] = xi2;
    e[3] = pos[j * 3] - xi0;
    e[4] = pos[j * 3 + 1] - xi1;
    e[5] = pos[j * 3 + 2] - xi2;
#pragma unroll
    for (int a = 0; a < 6; a++) {
      s1[a] += e[a];
#pragma unroll
      for (int b = 0; b < 6; b++) s2[a * 6 + b] = fmaf(e[a], e[b], s2[a * 6 + b]);
    }
  }
#pragma unroll
  for (int a = 0; a < 6; a++) {
#pragma unroll
    for (int m = 1; m < 64; m <<= 1) s1[a] += __shfl_xor(s1[a], m, 64);
  }
#pragma unroll
  for (int a = 0; a < 36; a++) {
#pragma unroll
    for (int m = 1; m < 64; m <<= 1) s2[a] += __shfl_xor(s2[a], m, 64);
  }
  if ((tid & 63) == 0) {
#pragma unroll
    for (int a = 0; a < 6; a++) red[w][a] = s1[a];
#pragma unroll
    for (int a = 0; a < 36; a++) red[w][6 + a] = s2[a];
  }
  __syncthreads();
  if (tid < 42) {
    double t = (double)red[0][tid] + (double)red[1][tid] + (double)red[2][tid] +
               (double)red[3][tid];
    Spart[(size_t)blockIdx.x * 42 + tid] = t;
  }
}

// ---------------------------------------------------------------------------
// kbn: stats reduce -> BN scale/shift; W1b pre-swizzle to B-frag bf16 hi/lo.
// ---------------------------------------------------------------------------
__global__ void kbn(const double* __restrict__ Spart, const float* __restrict__ W1a,
                    const float* __restrict__ b1a, const float* __restrict__ g1,
                    const float* __restrict__ be1, const float* __restrict__ W1b,
                    float* __restrict__ ss, unsigned short* __restrict__ Bh,
                    unsigned short* __restrict__ Bl) {
  __shared__ double S[42];
  const int c = threadIdx.x;  // 256 threads
  if (c < 42) {
    double t = 0.0;
    for (int b = 0; b < 128; b++) t += Spart[(size_t)b * 42 + c];
    S[c] = t;
  }
  for (int t = c; t < 4096; t += 256) {
    const int j = t & 7, L = (t >> 3) & 63, f = t >> 9;  // f = nt*2+ks
    const int nt = f >> 1, ks = f & 1;
    const int k = ks * 32 + (L >> 4) * 8 + j;
    const int n = nt * 16 + (L & 15);
    const float wv = W1b[k * 64 + n];
    const unsigned u = __float_as_uint(wv);
    const unsigned hb = (u + 0x7fffu + ((u >> 16) & 1u)) & 0xffff0000u;  // RNE bf16
    Bh[t] = (unsigned short)(hb >> 16);
    Bl[t] = (unsigned short)bf16rne(wv - __uint_as_float(hb));
  }
  __syncthreads();
  if (c < 64) {
    double w[6];
#pragma unroll
    for (int d = 0; d < 6; d++) w[d] = (double)W1a[d * 64 + c];
    double b = (double)b1a[c];
    const double invN = 1.0 / (double)((size_t)NPTS * NK);
    double m1 = 0.0;
#pragma unroll
    for (int d = 0; d < 6; d++) m1 += w[d] * S[d];
    m1 *= invN;
    double q = 0.0;
#pragma unroll
    for (int a = 0; a < 6; a++)
#pragma unroll
      for (int d = 0; d < 6; d++) q += w[a] * w[d] * S[6 + a * 6 + d];
    q *= invN;
    double mu = m1 + b;
    double eh2 = q + 2.0 * b * m1 + b * b;
    double var = eh2 - mu * mu;
    if (var < 0.0) var = 0.0;
    double inv = 1.0 / sqrt(var + 1e-5);
    double sc = (double)g1[c] * inv;
    ss[c] = (float)sc;
    ss[64 + c] = (float)((double)be1[c] - mu * sc);
  }
}

// ---------------------------------------------------------------------------
// EdgeConv1 fused — MFMA, XOR bank-swizzled staging (R21-verified).
// ---------------------------------------------------------------------------
#define EC1P 8
__global__ __launch_bounds__(256) void kec1(const float* __restrict__ pos,
                                            const int* __restrict__ idx,
                                            const float* __restrict__ ss,
                                            const float* __restrict__ W1a,
                                            const float* __restrict__ b1a,
                                            const unsigned short* __restrict__ Bh,
                                            const unsigned short* __restrict__ Bl,
                                            const float* __restrict__ b1b,
                                            float* __restrict__ x1) {
  __shared__ __align__(16) unsigned short Ah[4][3072];
  __shared__ __align__(16) unsigned short Al[4][3072];
  __shared__ float nbr[4][160];
  const int tid = threadIdx.x;
  const int lane = tid & 63;
  const int w = tid >> 6;
  const int p0 = blockIdx.x * EC1P + w * 2;  // this wave's 2 points

  unsigned short* ah = Ah[w];
  unsigned short* al = Al[w];
  float* nb = nbr[w];

  if (lane < 40) {
    const int j = idx[(size_t)p0 * NK + lane];
    nb[lane * 4 + 0] = pos[j * 3 + 0];
    nb[lane * 4 + 1] = pos[j * 3 + 1];
    nb[lane * 4 + 2] = pos[j * 3 + 2];
  }

  float wdf[3], wbt[3];
#pragma unroll
  for (int d = 0; d < 3; d++) {
    const float top = W1a[d * 64 + lane];
    const float bot = W1a[(3 + d) * 64 + lane];
    wdf[d] = top - bot;
    wbt[d] = bot;
  }
  const float b1 = b1a[lane];
  const float sc = ss[lane];
  const float sh = ss[64 + lane];
  // swizzled staging address components (write side)
  const int lanehi = (((lane & 31) >> 3) * 128) + ((lane >> 5) * 512);
  const int lanelo = lane & 7;
  const int g3w = ((lane & 31) >> 3) + ((lane >> 5) << 2);  // 128-group index
  __builtin_amdgcn_wave_barrier();

#pragma unroll
  for (int pp = 0; pp < 2; pp++) {
    const int p = p0 + pp;
    const float xi0 = pos[p * 3], xi1 = pos[p * 3 + 1], xi2 = pos[p * 3 + 2];
    const float pu = fmaf(xi2, wdf[2], fmaf(xi1, wdf[1], fmaf(xi0, wdf[0], b1)));
    for (int k = 0; k < NK; k++) {
      const int row = pp * NK + k;
      const float4 nbv = *(const float4*)&nb[row * 4];  // broadcast
      const float pv = fmaf(nbv.z, wbt[2], fmaf(nbv.y, wbt[1], nbv.x * wbt[0]));
      const float z = fmaxf(fmaf(pu + pv, sc, sh), 0.f);
      const unsigned u = __float_as_uint(z);
      const unsigned hb = (u + 0x7fffu + ((u >> 16) & 1u)) & 0xffff0000u;
      const int off =
          (row >> 4) * 1024 + lanehi + (((row & 15) ^ g3w) << 3) + lanelo;
      ah[off] = (unsigned short)(hb >> 16);
      al[off] = (unsigned short)bf16rne(z - __uint_as_float(hb));
    }
  }
  __builtin_amdgcn_wave_barrier();

  bf16x8 bh[4][2], bl[4][2];
#pragma unroll
  for (int nt = 0; nt < 4; nt++)
#pragma unroll
    for (int ks = 0; ks < 2; ks++) {
      const int base = ((nt * 2 + ks) * 64 + lane) * 8;
      bh[nt][ks] = *(const bf16x8*)&Bh[base];
      bl[nt][ks] = *(const bf16x8*)&Bl[base];
    }

  float pA[4], pB[4];
#pragma unroll
  for (int nt = 0; nt < 4; nt++) {
    pA[nt] = -FLT_MAX;
    pB[nt] = -FLT_MAX;
  }
  const int q4 = (lane >> 4) * 4;
  // swizzled fragment-read bases (read side): g3 = (lane>>4) + 4*ks
  const int rb0 = (lane >> 4) * 128 + (((lane & 15) ^ (lane >> 4)) << 3);
  const int rb1 =
      512 + (lane >> 4) * 128 + (((lane & 15) ^ (4 + (lane >> 4))) << 3);

#pragma unroll
  for (int mt = 0; mt < 3; mt++) {
    const bf16x8 a_h0 = *(const bf16x8*)&ah[mt * 1024 + rb0];
    const bf16x8 a_l0 = *(const bf16x8*)&al[mt * 1024 + rb0];
    const bf16x8 a_h1 = *(const bf16x8*)&ah[mt * 1024 + rb1];
    const bf16x8 a_l1 = *(const bf16x8*)&al[mt * 1024 + rb1];
#pragma unroll
    for (int nt = 0; nt < 4; nt++) {
      f32x4 C = {0.f, 0.f, 0.f, 0.f};
      C = __builtin_amdgcn_mfma_f32_16x16x32_bf16(a_h0, bh[nt][0], C, 0, 0, 0);
      C = __builtin_amdgcn_mfma_f32_16x16x32_bf16(a_h0, bl[nt][0], C, 0, 0, 0);
      C = __builtin_amdgcn_mfma_f32_16x16x32_bf16(a_l0, bh[nt][0], C, 0, 0, 0);
      C = __builtin_amdgcn_mfma_f32_16x16x32_bf16(a_h1, bh[nt][1], C, 0, 0, 0);
      C = __builtin_amdgcn_mfma_f32_16x16x32_bf16(a_h1, bl[nt][1], C, 0, 0, 0);
      C = __builtin_amdgcn_mfma_f32_16x16x32_bf16(a_l1, bh[nt][1], C, 0, 0, 0);
#pragma unroll
      for (int r = 0; r < 4; r++) {
        const int row = mt * 16 + q4 + r;
        const float vv = C[r];
        if (row < NK) pA[nt] = fmaxf(pA[nt], vv);
        if (row >= NK && row < 2 * NK) pB[nt] = fmaxf(pB[nt], vv);
      }
    }
  }
#pragma unroll
  for (int s = 16; s < 64; s <<= 1) {
#pragma unroll
    for (int nt = 0; nt < 4; nt++) {
      pA[nt] = fmaxf(pA[nt], __shfl_xor(pA[nt], s, 64));
      pB[nt] = fmaxf(pB[nt], __shfl_xor(pB[nt], s, 64));
    }
  }
  if (lane < 16) {
#pragma unroll
    for (int nt = 0; nt < 4; nt++) {
      const float bb = b1b[nt * 16 + lane];
      x1[(size_t)p0 * 64 + nt * 16 + lane] = pA[nt] + bb;
      x1[(size_t)(p0 + 1) * 64 + nt * 16 + lane] = pB[nt] + bb;
    }
  }
}

// v[j,c] = x1_j . W2[64+d][c]
__global__ __launch_bounds__(256) void kv(const float* __restrict__ x1,
                                          const float* __restrict__ W2,
                                          float* __restrict__ v) {
  const int c = threadIdx.x & 127;
  const int sub = threadIdx.x >> 7;
  float wv[64];
#pragma unroll
  for (int d = 0; d < 64; d++) wv[d] = W2[(64 + d) * 128 + c];
  const int pbase = blockIdx.x * 64 + sub * 32;
  for (int i = 0; i < 32; i++) {
    const int p = pbase + i;
    const float4* xr = (const float4*)(x1 + (size_t)p * 64);
    float a0 = 0.f, a1 = 0.f;
#pragma unroll
    for (int dq = 0; dq < 16; dq++) {
      float4 xv = xr[dq];
      a0 = fmaf(xv.x, wv[dq * 4 + 0], a0);
      a1 = fmaf(xv.y, wv[dq * 4 + 1], a1);
      a0 = fmaf(xv.z, wv[dq * 4 + 2], a0);
      a1 = fmaf(xv.w, wv[dq * 4 + 3], a1);
    }
    v[(size_t)p * 128 + c] = a0 + a1;
  }
}

// Bc (192x128) and const bias cb (128)
__global__ __launch_bounds__(256) void kprep(const float* __restrict__ W2,
                                             const float* __restrict__ Wl,
                                             const float* __restrict__ b2,
                                             const float* __restrict__ bl,
                                             float* __restrict__ Bc,
                                             float* __restrict__ cb) {
  const int t = blockIdx.x * 256 + threadIdx.x;  // 8192
  const int d = t >> 7, c = t & 127;
  float s = Wl[d * 128 + c];
  for (int e = 0; e < 128; e++)
    s = fmaf(W2[d * 128 + e] - W2[(64 + d) * 128 + e], Wl[(64 + e) * 128 + c], s);
  Bc[d * 128 + c] = s;
  Bc[(64 + 2 * d) * 128 + c] = Wl[(64 + 2 * d) * 128 + c];
  Bc[(64 + 2 * d + 1) * 128 + c] = Wl[(64 + 2 * d + 1) * 128 + c];
  if (d == 0) {
    float sb = bl[c];
    for (int e = 0; e < 128; e++) sb = fmaf(b2[e], Wl[(64 + e) * 128 + c], sb);
    cb[c] = sb;
  }
}

// ---------------------------------------------------------------------------
// kprep2: pack Bc (192x128 fp32) into MFMA B-fragment order, bf16 hi/lo.
// ---------------------------------------------------------------------------
__global__ __launch_bounds__(256) void kprep2(const float* __restrict__ Bc,
                                              unsigned short* __restrict__ Bch,
                                              unsigned short* __restrict__ Bcl) {
  const int t = blockIdx.x * 256 + threadIdx.x;  // 24576
  const int j = t & 7, L = (t >> 3) & 63, f = t >> 9;  // f = nt*6+kc in 0..47
  const int nt = f / 6, kc = f % 6;
  const int k = kc * 32 + ((L >> 4) << 3) + j;
  const int n = nt * 16 + (L & 15);
  const float wv = Bc[k * 128 + n];
  const unsigned u = __float_as_uint(wv);
  const unsigned hb = (u + 0x7fffu + ((u >> 16) & 1u)) & 0xffff0000u;
  Bch[t] = (unsigned short)(hb >> 16);
  Bcl[t] = (unsigned short)bf16rne(wv - __uint_as_float(hb));
}

// ---------------------------------------------------------------------------
// kgemm v4 (R20-verified): coalesced gather + LDS transpose + MFMA.
// ---------------------------------------------------------------------------
__global__ __launch_bounds__(256) void kgemm(const float* __restrict__ x1,
                                             const float* __restrict__ v,
                                             const int* __restrict__ idx,
                                             const unsigned short* __restrict__ Bch,
                                             const unsigned short* __restrict__ Bcl,
                                             float* __restrict__ partial) {
  __shared__ int idxs[4][320];
  __shared__ __align__(16) float vlds[4][16][132];  // padded: 2-way on write/read
  __shared__ float red[4][8][16];
  const int tid = threadIdx.x;
  const int lane = tid & 63;
  const int w = tid >> 6;
  const int cloud = blockIdx.x & 31;  // XCD-local cloud assignment
  const int mb = blockIdx.x >> 5;
  const int pbase = cloud * 1024 + mb * 64;
  const int mrow = lane & 15, gsel = lane >> 4;
  const int m = w * 16 + mrow;  // this lane's local row (0..63)

  // stage this wave's 16x20 neighbor indices (320 consecutive ints)
#pragma unroll
  for (int r = 0; r < 5; r++)
    idxs[w][r * 64 + lane] = idx[(size_t)(pbase + w * 16) * NK + r * 64 + lane];
  __builtin_amdgcn_wave_barrier();

  // Phase A: per point, 20 fully-coalesced row loads (wave-uniform row id,
  // 64 lanes x 8B = 512B contiguous), fmax-accumulate, stash to LDS.
  for (int pt = 0; pt < 16; pt++) {
    const int* ip = &idxs[w][pt * NK];
    float m0 = -FLT_MAX, m1 = -FLT_MAX;
#pragma unroll
    for (int k = 0; k < NK; k++) {
      const float2 val = *(const float2*)(v + (size_t)ip[k] * 128 + lane * 2);
      m0 = fmaxf(m0, val.x);
      m1 = fmaxf(m1, val.y);
    }
    *(float2*)&vlds[w][pt][lane * 2] = make_float2(m0, m1);
  }
  __builtin_amdgcn_wave_barrier();

  bf16x8 aH[6], aL[6];
  // x1 part (K rows 0..63): kc = 0,1 — direct load, fragment in regs.
#pragma unroll
  for (int kc = 0; kc < 2; kc++) {
    const float4* xr =
        (const float4*)(x1 + (size_t)(pbase + m) * 64 + kc * 32 + gsel * 8);
    const float4 v0 = xr[0], v1 = xr[1];
    const float vv[8] = {v0.x, v0.y, v0.z, v0.w, v1.x, v1.y, v1.z, v1.w};
    bf16x8 h, l;
#pragma unroll
    for (int j = 0; j < 8; j++) {
      const unsigned u = __float_as_uint(vv[j]);
      const unsigned hb = (u + 0x7fffu + ((u >> 16) & 1u)) & 0xffff0000u;
      h[j] = (short)(hb >> 16);
      l[j] = (short)bf16rne(vv[j] - __uint_as_float(hb));
    }
    aH[kc] = h;
    aL[kc] = l;
  }

  // Phase B: gather part (K rows 64..191) — read fragments from LDS.
#pragma unroll
  for (int g = 0; g < 4; g++) {
    const float* src = &vlds[w][mrow][g * 32 + gsel * 8];
    const float4 a = *(const float4*)(src);
    const float4 b = *(const float4*)(src + 4);
    const float vv[8] = {a.x, a.y, a.z, a.w, b.x, b.y, b.z, b.w};
    bf16x8 h, l;
#pragma unroll
    for (int j = 0; j < 8; j++) {
      const unsigned u = __float_as_uint(vv[j]);
      const unsigned hb = (u + 0x7fffu + ((u >> 16) & 1u)) & 0xffff0000u;
      h[j] = (short)(hb >> 16);
      l[j] = (short)bf16rne(vv[j] - __uint_as_float(hb));
    }
    aH[2 + g] = h;
    aL[2 + g] = l;
  }

  // Phase C: MFMA GEMM — wave owns m-tile w; 8 nt x 6 kc x 3-product split.
  f32x4 acc[8];
#pragma unroll
  for (int nt = 0; nt < 8; nt++) acc[nt] = {0.f, 0.f, 0.f, 0.f};
#pragma unroll
  for (int nt = 0; nt < 8; nt++) {
#pragma unroll
    for (int kc = 0; kc < 6; kc++) {
      const size_t bo = ((size_t)(nt * 6 + kc) * 64 + lane) * 8;
      const bf16x8 b_h = *(const bf16x8*)&Bch[bo];
      const bf16x8 b_l = *(const bf16x8*)&Bcl[bo];
      acc[nt] = __builtin_amdgcn_mfma_f32_16x16x32_bf16(aH[kc], b_h, acc[nt], 0, 0, 0);
      acc[nt] = __builtin_amdgcn_mfma_f32_16x16x32_bf16(aH[kc], b_l, acc[nt], 0, 0, 0);
      acc[nt] = __builtin_amdgcn_mfma_f32_16x16x32_bf16(aL[kc], b_h, acc[nt], 0, 0, 0);
    }
  }

  // Epilogue: max over this wave's 16 rows (in-reg + shfl), then cross-wave.
#pragma unroll
  for (int nt = 0; nt < 8; nt++) {
    float rm = fmaxf(fmaxf(acc[nt][0], acc[nt][1]), fmaxf(acc[nt][2], acc[nt][3]));
    rm = fmaxf(rm, __shfl_xor(rm, 16, 64));
    rm = fmaxf(rm, __shfl_xor(rm, 32, 64));
    if (lane < 16) red[w][nt][lane] = rm;
  }
  __syncthreads();
  if (tid < 128) {
    const int nt = tid >> 4, cc = tid & 15;
    const float m4 = fmaxf(fmaxf(red[0][nt][cc], red[1][nt][cc]),
                           fmaxf(red[2][nt][cc], red[3][nt][cc]));
    partial[(size_t)(cloud * 16 + mb) * 128 + tid] = m4;
  }
}

__global__ __launch_bounds__(256) void kred(const float* __restrict__ partial,
                                            const float* __restrict__ cb,
                                            float* __restrict__ out) {
  int t = blockIdx.x * 256 + threadIdx.x;  // 4096
  int b = t >> 7, c = t & 127;
  float m = -FLT_MAX;
#pragma unroll
  for (int mb = 0; mb < 16; mb++) m = fmaxf(m, partial[(size_t)(b * 16 + mb) * 128 + c]);
  out[t] = m + cb[c];
}

// ---------------------------------------------------------------------------
extern "C" void kernel_launch(void* const* d_in, const int* in_sizes, int n_in,
                              void* d_out, int out_size, void* d_ws, size_t ws_size,
                              hipStream_t stream) {
  const float* pos = (const float*)d_in[0];
  const float* W1a = (const float*)d_in[1];
  const float* b1a = (const float*)d_in[2];
  const float* g1 = (const float*)d_in[3];
  const float* be1 = (const float*)d_in[4];
  const float* W1b = (const float*)d_in[5];
  const float* b1b = (const float*)d_in[6];
  const float* W2 = (const float*)d_in[7];
  const float* b2 = (const float*)d_in[8];
  const float* Wl = (const float*)d_in[9];
  const float* bl = (const float*)d_in[10];
  float* out = (float*)d_out;

  // Base workspace (floats). Layout kept from prior rounds (D now unused).
  float* ws = (float*)d_ws;
  float* x1 = ws;                                        // 2,097,152
  float* v = ws + 2097152;                               // 4,194,304
  int* idx = (int*)(ws + 6291456);                       // 655,360
  float* d2b = ws + 6946816;                             // 32,768
  double* Spart = (double*)(ws + 6979584);               // 10,752
  float* Bc = ws + 6990336;                              // 24,576
  float* cb = ws + 7014912;                              // 128
  float* ss = ws + 7015040;                              // 128
  unsigned short* Bh = (unsigned short*)(ws + 7015168);  // 2048 fl
  unsigned short* Bl = (unsigned short*)(ws + 7017216);  // 2048 fl
  float* partial = ws + 7019264;                         // 65,536
  unsigned short* Xfh = (unsigned short*)(ws + 7084800); // 1,048,576 fl
  unsigned short* Xfl = (unsigned short*)(ws + 8133376); // 1,048,576 fl
  unsigned short* Bch2 = (unsigned short*)(ws + 9181952); // 12,288 fl
  unsigned short* Bcl2 = (unsigned short*)(ws + 9194240); // 12,288 fl
  const size_t base = 9206528;

  if (ws_size < base * sizeof(float)) return;  // fail soft

  // --- layer 1: fused kNN on pos (3D) — one point per wave ---
  kd2<<<128, 256, 0, stream>>>(pos, 3, d2b);
  kfsel1<<<NB * 128, 512, 0, stream>>>(pos, d2b, idx);

  // --- EdgeConv1 (analytic BN + MFMA edge-GEMM) ---
  kstats<<<128, 256, 0, stream>>>(pos, idx, Spart);
  kbn<<<1, 256, 0, stream>>>(Spart, W1a, b1a, g1, be1, W1b, ss, Bh, Bl);
  kec1<<<NPTS / EC1P, 256, 0, stream>>>(pos, idx, ss, W1a, b1a, Bh, Bl, b1b, x1);

  // --- layer 2: fused kNN on x1 (64D) — MFMA distance + select, no D ---
  kd2<<<128, 256, 0, stream>>>(x1, 64, d2b);
  kxprep<<<1024, 256, 0, stream>>>(x1, Xfh, Xfl);
  kdsel2<<<NB * 64, 512, 0, stream>>>(Xfh, Xfl, d2b, idx);

  // --- EdgeConv2 factored + fused final linear (MFMA) + pool ---
  kv<<<512, 256, 0, stream>>>(x1, W2, v);
  kprep<<<32, 256, 0, stream>>>(W2, Wl, b2, bl, Bc, cb);
  kprep2<<<96, 256, 0, stream>>>(Bc, Bch2, Bcl2);
  kgemm<<<512, 256, 0, stream>>>(x1, v, idx, Bch2, Bcl2, partial);
  kred<<<16, 256, 0, stream>>>(partial, cb, out);
}

// Round 12
// 326.354 us; speedup vs baseline: 1.0512x; 1.0512x over previous
//
#include <hip/hip_runtime.h>
#include <cfloat>
#include <cstdint>

#define NB 32
#define NP 1024
#define NK 20
#define NPTS 32768  // NB*NP

typedef __attribute__((ext_vector_type(8))) short bf16x8;
typedef __attribute__((ext_vector_type(4))) float f32x4;

__device__ __forceinline__ unsigned bf16rne(float v) {
  const unsigned u = __float_as_uint(v);
  return (u + 0x7fffu + ((u >> 16) & 1u)) >> 16;
}

// inverse of the sortable transform u ^= (int(u)>>31 | 0x80000000)
__device__ __forceinline__ float unsort_f(unsigned s) {
  const unsigned m = (~(unsigned)((int)s >> 31)) | 0x80000000u;
  return __uint_as_float(s ^ m);
}

// ---------------------------------------------------------------------------
// d2[p] = sum x^2 (fp32 exact).
// ---------------------------------------------------------------------------
__global__ __launch_bounds__(256) void kd2(const float* __restrict__ x, int dim,
                                           float* __restrict__ d2) {
  int p = blockIdx.x * 256 + threadIdx.x;
  if (p >= NPTS) return;
  if (dim == 64) {
    const float4* xr = (const float4*)(x + (size_t)p * 64);
    float s = 0.f;
#pragma unroll
    for (int dq = 0; dq < 16; dq++) {
      float4 v = xr[dq];
      s = fmaf(v.x, v.x, s);
      s = fmaf(v.y, v.y, s);
      s = fmaf(v.z, v.z, s);
      s = fmaf(v.w, v.w, s);
    }
    d2[p] = s;
  } else {
    float s = 0.f;
#pragma unroll
    for (int d = 0; d < 3; d++) {
      float v = x[p * 3 + d];
      s = fmaf(v, v, s);
    }
    d2[p] = s;
  }
}

// ---------------------------------------------------------------------------
// kxprep: convert x1 into MFMA fragment order, bf16 hi/lo (HW-validated).
// ---------------------------------------------------------------------------
__global__ __launch_bounds__(256) void kxprep(const float* __restrict__ x,
                                              unsigned short* __restrict__ Xh,
                                              unsigned short* __restrict__ Xl) {
  const int t = blockIdx.x * 256 + threadIdx.x;  // 262144
  const int p = t >> 3, g = t & 7;               // k = g*8 + j
  const float4* xr = (const float4*)(x + (size_t)p * 64 + g * 8);
  const float4 v0 = xr[0];
  const float4 v1 = xr[1];
  const float vv[8] = {v0.x, v0.y, v0.z, v0.w, v1.x, v1.y, v1.z, v1.w};
  unsigned short h[8], l[8];
#pragma unroll
  for (int j = 0; j < 8; j++) {
    const float z = vv[j];
    const unsigned u = __float_as_uint(z);
    const unsigned hb = (u + 0x7fffu + ((u >> 16) & 1u)) & 0xffff0000u;
    h[j] = (unsigned short)(hb >> 16);
    l[j] = (unsigned short)bf16rne(z - __uint_as_float(hb));
  }
  const int off = (((p >> 4) * 2 + (g >> 2)) * 64 + ((g & 3) << 4) + (p & 15)) * 8;
  *(uint4*)&Xh[off] = *(const uint4*)&h[0];
  *(uint4*)&Xl[off] = *(const uint4*)&l[0];
}

// ---------------------------------------------------------------------------
// select20k (R25): exact top-20 SET on pre-transformed sortable u32 keys.
// Stage 1: interp-search pivot with cnt in [20,64] (ballot->s_bcnt1 counts).
// Stage 2: compact candidates (<=64) to one per lane in LDS + rank pass
// (R24-verified). Fallback (value plateau, rare): u64 bisect on the fly.
// ---------------------------------------------------------------------------
__device__ __forceinline__ void select20k(const unsigned* k32, unsigned long long* w,
                                          int lane, int pg, int gbase,
                                          int* __restrict__ idxo) {
  // lane-local min; butterfly: global min (mn) and max-of-lane-mins (mlm).
  unsigned lmn = k32[0];
#pragma unroll
  for (int ii = 1; ii < 16; ii++) lmn = k32[ii] < lmn ? k32[ii] : lmn;
  unsigned mn = lmn, mlm = lmn;
#pragma unroll
  for (int s = 1; s < 64; s <<= 1) {
    const unsigned a = __shfl_xor(mn, s, 64);
    const unsigned b = __shfl_xor(mlm, s, 64);
    mn = a < mn ? a : mn;
    mlm = b > mlm ? b : mlm;
  }
  // Stage 1. Invariants: cnt(<lo32) < 20, cnt(<hi32) > 64.
  unsigned lo32 = mn;                                      // cnt == 0
  unsigned long long hi32 = (unsigned long long)mlm + 1;   // cnt(<hi32) >= 64
  float flo = unsort_f(mn), fhi = unsort_f(mlm);
  float clo = 0.f, chi = 140.f;  // count estimates at flo/fhi (chi is a guess)
  unsigned m32 = 0;
  bool found = false;
  for (int it = 0; it < 40; ++it) {
    if (hi32 - (unsigned long long)lo32 <= 1) break;  // plateau -> fallback
    unsigned m;
    if (it < 6) {
      float fr = (42.f - clo) / (chi - clo);
      fr = fr < 0.04f ? 0.04f : (fr > 0.96f ? 0.96f : fr);
      const float pf = fmaf(fhi - flo, fr, flo);
      unsigned u = __float_as_uint(pf);
      u ^= (((int)u >> 31) | 0x80000000u);
      m = u;
      if (m <= lo32) m = lo32 + 1;                       // strict interior
      if ((unsigned long long)m >= hi32) m = (unsigned)(hi32 - 1);
    } else {
      m = (unsigned)(lo32 + ((hi32 - lo32) >> 1));
    }
    int cnt = 0;
#pragma unroll
    for (int ii = 0; ii < 16; ii++) cnt += __popcll(__ballot(k32[ii] < m));
    if (cnt < 20) {
      lo32 = m;
      flo = unsort_f(m);
      clo = (float)cnt;
    } else if (cnt > 64) {
      hi32 = m;
      fhi = unsort_f(m);
      chi = (float)cnt;
    } else {
      m32 = m;
      found = true;
      break;
    }
  }

  if (found) {
    // candidates: k32 < m32, total in [20,64] -> compact to one per lane.
    unsigned mask = 0;
#pragma unroll
    for (int ii = 0; ii < 16; ii++) mask |= (k32[ii] < m32) ? (1u << ii) : 0u;
    const int lc = __popc(mask);
    int x = lc;
#pragma unroll
    for (int s = 1; s < 64; s <<= 1) {
      const int y = __shfl_up(x, s, 64);
      if (lane >= s) x += y;
    }
    int off = x - lc;  // exclusive prefix; total <= 64 so off stays < 64
    w[lane] = ~0ULL;
    __builtin_amdgcn_wave_barrier();
#pragma unroll
    for (int i = 0; i < 4; i++)
#pragma unroll
      for (int j = 0; j < 4; j++) {
        const int ii = i * 4 + j;
        if ((mask & (1u << ii)) && off < 64) {
          w[off] = ((unsigned long long)k32[ii] << 10) |
                   (unsigned)(i * 256 + (lane << 2) + j);
          off++;
        }
      }
    __builtin_amdgcn_wave_barrier();
    const unsigned long long K = w[lane];  // pad lanes hold ~0ULL
    // Rank pass (R24-verified): 64 broadcast LDS reads, fully pipelined.
    int rank = 0;
#pragma unroll
    for (int m = 0; m < 64; m++) rank += (K > w[m]) ? 1 : 0;
    if (K != ~0ULL && rank < NK)
      idxo[(size_t)pg * NK + rank] = gbase + (int)(K & 1023u);
  } else {
    // plateau fallback: bisect full u64 keys (distinct -> exact cnt==20
    // reachable), keys rebuilt on the fly to keep VGPR pressure low.
    unsigned long long lo64 = ((unsigned long long)lo32) << 10;  // cnt < 20
    unsigned long long hi64 = hi32 << 10;                        // cnt > 64
    unsigned long long cut = hi64;
    for (int it = 0; it < 48 && (hi64 - lo64) > 1; ++it) {
      const unsigned long long m = lo64 + ((hi64 - lo64) >> 1);
      int cnt = 0;
#pragma unroll
      for (int ii = 0; ii < 16; ii++) {
        const unsigned long long key =
            ((unsigned long long)k32[ii] << 10) |
            (unsigned)(((ii >> 2) << 8) + (lane << 2) + (ii & 3));
        cnt += __popcll(__ballot(key < m));
      }
      if (cnt == 20) {
        cut = m;
        break;
      }
      if (cnt < 20)
        lo64 = m;
      else
        hi64 = m;
      cut = hi64;
    }
    int base = 0;
#pragma unroll
    for (int ii = 0; ii < 16; ii++) {
      const unsigned long long key =
          ((unsigned long long)k32[ii] << 10) |
          (unsigned)(((ii >> 2) << 8) + (lane << 2) + (ii & 3));
      const unsigned long long b = __ballot(key < cut);
      if (key < cut) {
        const int slot = base + __builtin_amdgcn_mbcnt_hi(
                                    (unsigned)(b >> 32),
                                    __builtin_amdgcn_mbcnt_lo((unsigned)b, 0));
        idxo[(size_t)pg * NK + slot] = gbase + (int)(key & 1023u);
      }
      base += __popcll(b);
    }
  }
}

// float-input wrapper (kfsel1 path): transform then select on keys.
__device__ __forceinline__ void select20(const float* dv, unsigned long long* w,
                                         int lane, int pg, int gbase,
                                         int* __restrict__ idxo) {
  unsigned k32[16];
#pragma unroll
  for (int ii = 0; ii < 16; ii++) {
    unsigned u = __float_as_uint(dv[ii]);
    u ^= (((int)u >> 31) | 0x80000000u);  // sortable transform
    k32[ii] = u;
  }
  select20k(k32, w, lane, pg, gbase, idxo);
}

// ---------------------------------------------------------------------------
// kfsel1 v2: fused dim=3 distance + top-20 select, one point per wave.
// ---------------------------------------------------------------------------
__global__ __launch_bounds__(512) void kfsel1(const float* __restrict__ pos,
                                              const float* __restrict__ d2,
                                              int* __restrict__ idxo) {
  __shared__ float px[1024], py[1024], pz[1024], pd2[1024];
  __shared__ unsigned long long lw[8][64];
  const int tid = threadIdx.x;
  const int lane = tid & 63;
  const int w = tid >> 6;
  const int cloud = blockIdx.x >> 7;  // 128 blocks per cloud
  const int mb = blockIdx.x & 127;
  const int cb = cloud << 10;

  if (tid < 256) {  // stage cloud: thread t -> points 4t..4t+3, SoA transpose
    const float4* ppos = (const float4*)(pos + (size_t)cb * 3 + tid * 12);
    const float4 a = ppos[0], b = ppos[1], c = ppos[2];
    *(float4*)&px[tid * 4] = make_float4(a.x, a.w, b.z, c.y);
    *(float4*)&py[tid * 4] = make_float4(a.y, b.x, b.w, c.z);
    *(float4*)&pz[tid * 4] = make_float4(a.z, b.y, c.x, c.w);
  }
  *(float2*)&pd2[tid * 2] = *(const float2*)(d2 + cb + tid * 2);
  __syncthreads();

  const int pl = mb * 8 + w;  // this wave's point (wave-uniform)
  const float xi0 = px[pl], xi1 = py[pl], xi2 = pz[pl];
  const float dp = pd2[pl];
  float dv[16];
#pragma unroll
  for (int i = 0; i < 4; i++) {  // q = i*256 + lane*4 + j (select20 mapping)
    const float4 X = *(const float4*)&px[i * 256 + lane * 4];
    const float4 Y = *(const float4*)&py[i * 256 + lane * 4];
    const float4 Z = *(const float4*)&pz[i * 256 + lane * 4];
    const float4 Q = *(const float4*)&pd2[i * 256 + lane * 4];
    const float xs[4] = {X.x, X.y, X.z, X.w};
    const float ys[4] = {Y.x, Y.y, Y.z, Y.w};
    const float zs[4] = {Z.x, Z.y, Z.z, Z.w};
    const float qs[4] = {Q.x, Q.y, Q.z, Q.w};
#pragma unroll
    for (int j = 0; j < 4; j++) {
      float acc = 0.f;
      acc = fmaf(xi0, xs[j], acc);
      acc = fmaf(xi1, ys[j], acc);
      acc = fmaf(xi2, zs[j], acc);
      dv[i * 4 + j] = fmaf(-2.f, acc, dp + qs[j]);
    }
  }
  select20(dv, lw[w], lane, cb + pl, cb, idxo);
}

// ---------------------------------------------------------------------------
// kdsel2 v3b (R26): half-strip double-pass, NO min-wave pin.
// R10 post-mortem: launch_bounds(512,8) forced VGPR->32, spilling kk0 +
// select state to scratch (WRITE_SIZE 2.6MB -> 244MB, 350MB spill traffic
// = the whole regression). Algorithm itself verified correct (passed,
// absmax unchanged). v3b: identical code, plain launch_bounds(512) ->
// compiler picks ~68-72 VGPR, no spills; 36KB LDS -> 3-4 blocks/CU
// (24-32 waves) vs v1's 2 blocks (16 waves).
// ---------------------------------------------------------------------------
__global__ __launch_bounds__(512) void kdsel2(const unsigned short* __restrict__ Xh,
                                              const unsigned short* __restrict__ Xl,
                                              const float* __restrict__ d2,
                                              int* __restrict__ idxo) {
  __shared__ __align__(16) float Dl[16][512];
  __shared__ unsigned long long lw[8][64];
  const int lane = threadIdx.x & 63;
  const int w = threadIdx.x >> 6;
  const int cloud = blockIdx.x & 31;  // XCD-local cloud assignment
  const int rb = blockIdx.x >> 5;     // 0..63 row-block within cloud
  const int cb = cloud * 1024;
  const int rowb = rb * 16;           // local row base

  // A fragments for the block's 16 rows (wave-duplicated; L2 broadcast)
  bf16x8 Ah[2], Al[2];
#pragma unroll
  for (int ks = 0; ks < 2; ks++) {
    const int tg = (cb + rowb) >> 4;
    const size_t base = ((size_t)(tg * 2 + ks) * 64 + lane) * 8;
    Ah[ks] = *(const bf16x8*)&Xh[base];
    Al[ks] = *(const bf16x8*)&Xl[base];
  }
  float d2r[4];
#pragma unroll
  for (int r = 0; r < 4; r++) d2r[r] = d2[cb + rowb + (lane >> 4) * 4 + r];

  unsigned kk0[2][8];  // half-0 keys for this wave's 2 points

  for (int h = 0; h < 2; h++) {
    // distance half-strip: wave w owns 4 tiles (64 cols of this half)
#pragma unroll
    for (int nt = 0; nt < 4; nt++) {
      const int c0 = w * 64 + nt * 16;   // local col within half
      const int cg = cb + h * 512 + c0;  // global col
      bf16x8 Bh2[2], Bl2[2];
#pragma unroll
      for (int ks = 0; ks < 2; ks++) {
        const int tg = cg >> 4;
        const size_t base = ((size_t)(tg * 2 + ks) * 64 + lane) * 8;
        Bh2[ks] = *(const bf16x8*)&Xh[base];
        Bl2[ks] = *(const bf16x8*)&Xl[base];
      }
      const float d2c = d2[cg + (lane & 15)];
      f32x4 C = {0.f, 0.f, 0.f, 0.f};
      C = __builtin_amdgcn_mfma_f32_16x16x32_bf16(Ah[0], Bh2[0], C, 0, 0, 0);
      C = __builtin_amdgcn_mfma_f32_16x16x32_bf16(Ah[0], Bl2[0], C, 0, 0, 0);
      C = __builtin_amdgcn_mfma_f32_16x16x32_bf16(Al[0], Bh2[0], C, 0, 0, 0);
      C = __builtin_amdgcn_mfma_f32_16x16x32_bf16(Ah[1], Bh2[1], C, 0, 0, 0);
      C = __builtin_amdgcn_mfma_f32_16x16x32_bf16(Ah[1], Bl2[1], C, 0, 0, 0);
      C = __builtin_amdgcn_mfma_f32_16x16x32_bf16(Al[1], Bh2[1], C, 0, 0, 0);
#pragma unroll
      for (int r = 0; r < 4; r++) {
        const int row = (lane >> 4) * 4 + r;
        const int col = c0 + (lane & 15);
        Dl[row][col ^ ((row & 7) << 2)] = fmaf(-2.f, C[r], d2r[r] + d2c);
      }
    }
    __syncthreads();
    if (h == 0) {
      // extract half-0 keys for BOTH points before the strip is overwritten
#pragma unroll
      for (int pp = 0; pp < 2; pp++) {
        const int pl = w * 2 + pp;
        const int s = (pl & 7) << 2;
#pragma unroll
        for (int i2 = 0; i2 < 2; i2++) {
          const float4 d4 = *(const float4*)&Dl[pl][(i2 * 256 + lane * 4) ^ s];
          const float dvv[4] = {d4.x, d4.y, d4.z, d4.w};
#pragma unroll
          for (int j = 0; j < 4; j++) {
            unsigned u = __float_as_uint(dvv[j]);
            u ^= (((int)u >> 31) | 0x80000000u);
            kk0[pp][i2 * 4 + j] = u;
          }
        }
      }
      __syncthreads();
    }
  }

  // strip holds half-1 and stays intact through both selects.
  for (int pp = 0; pp < 2; pp++) {
    const int pl = w * 2 + pp;  // local point 0..15 (wave-uniform)
    const int s = (pl & 7) << 2;
    unsigned k32[16];
#pragma unroll
    for (int ii = 0; ii < 8; ii++) k32[ii] = kk0[pp][ii];
#pragma unroll
    for (int i2 = 0; i2 < 2; i2++) {
      const float4 d4 = *(const float4*)&Dl[pl][(i2 * 256 + lane * 4) ^ s];
      const float dvv[4] = {d4.x, d4.y, d4.z, d4.w};
#pragma unroll
      for (int j = 0; j < 4; j++) {
        unsigned u = __float_as_uint(dvv[j]);
        u ^= (((int)u >> 31) | 0x80000000u);
        k32[8 + i2 * 4 + j] = u;
      }
    }
    select20k(k32, lw[w], lane, cb + rowb + pl, cb, idxo);
  }
}

// ---------------------------------------------------------------------------
// Edge moments, atomic-free.
// ---------------------------------------------------------------------------
__global__ __launch_bounds__(256) void kstats(const float* __restrict__ pos,
                                              const int* __restrict__ idx,
                                              double* __restrict__ Spart) {
  __shared__ float red[4][42];
  const int tid = threadIdx.x;
  const int w = tid >> 6;
  int p = blockIdx.x * 256 + tid;
  float xi0 = pos[p * 3], xi1 = pos[p * 3 + 1], xi2 = pos[p * 3 + 2];
  float s1[6];
  float s2[36];
#pragma unroll
  for (int a = 0; a < 6; a++) s1[a] = 0.f;
#pragma unroll
  for (int a = 0; a < 36; a++) s2[a] = 0.f;
  for (int k = 0; k < NK; k++) {
    int j = idx[p * NK + k];
    float e[6];
    e[0] = xi0;
    e[1] = xi1;
    e[2] = xi2;
    e[3] = pos[j * 3] - xi0;
    e[4] = pos[j * 3 + 1] - xi1;
    e[5] = pos[j * 3 + 2] - xi2;
#pragma unroll
    for (int a = 0; a < 6; a++) {
      s1[a] += e[a];
#pragma unroll
      for (int b = 0; b < 6; b++) s2[a * 6 + b] = fmaf(e[a], e[b], s2[a * 6 + b]);
    }
  }
#pragma unroll
  for (int a = 0; a < 6; a++) {
#pragma unroll
    for (int m = 1; m < 64; m <<= 1) s1[a] += __shfl_xor(s1[a], m, 64);
  }
#pragma unroll
  for (int a = 0; a < 36; a++) {
#pragma unroll
    for (int m = 1; m < 64; m <<= 1) s2[a] += __shfl_xor(s2[a], m, 64);
  }
  if ((tid & 63) == 0) {
#pragma unroll
    for (int a = 0; a < 6; a++) red[w][a] = s1[a];
#pragma unroll
    for (int a = 0; a < 36; a++) red[w][6 + a] = s2[a];
  }
  __syncthreads();
  if (tid < 42) {
    double t = (double)red[0][tid] + (double)red[1][tid] + (double)red[2][tid] +
               (double)red[3][tid];
    Spart[(size_t)blockIdx.x * 42 + tid] = t;
  }
}

// ---------------------------------------------------------------------------
// kbn: stats reduce -> BN scale/shift; W1b pre-swizzle to B-frag bf16 hi/lo.
// ---------------------------------------------------------------------------
__global__ void kbn(const double* __restrict__ Spart, const float* __restrict__ W1a,
                    const float* __restrict__ b1a, const float* __restrict__ g1,
                    const float* __restrict__ be1, const float* __restrict__ W1b,
                    float* __restrict__ ss, unsigned short* __restrict__ Bh,
                    unsigned short* __restrict__ Bl) {
  __shared__ double S[42];
  const int c = threadIdx.x;  // 256 threads
  if (c < 42) {
    double t = 0.0;
    for (int b = 0; b < 128; b++) t += Spart[(size_t)b * 42 + c];
    S[c] = t;
  }
  for (int t = c; t < 4096; t += 256) {
    const int j = t & 7, L = (t >> 3) & 63, f = t >> 9;  // f = nt*2+ks
    const int nt = f >> 1, ks = f & 1;
    const int k = ks * 32 + (L >> 4) * 8 + j;
    const int n = nt * 16 + (L & 15);
    const float wv = W1b[k * 64 + n];
    const unsigned u = __float_as_uint(wv);
    const unsigned hb = (u + 0x7fffu + ((u >> 16) & 1u)) & 0xffff0000u;  // RNE bf16
    Bh[t] = (unsigned short)(hb >> 16);
    Bl[t] = (unsigned short)bf16rne(wv - __uint_as_float(hb));
  }
  __syncthreads();
  if (c < 64) {
    double w[6];
#pragma unroll
    for (int d = 0; d < 6; d++) w[d] = (double)W1a[d * 64 + c];
    double b = (double)b1a[c];
    const double invN = 1.0 / (double)((size_t)NPTS * NK);
    double m1 = 0.0;
#pragma unroll
    for (int d = 0; d < 6; d++) m1 += w[d] * S[d];
    m1 *= invN;
    double q = 0.0;
#pragma unroll
    for (int a = 0; a < 6; a++)
#pragma unroll
      for (int d = 0; d < 6; d++) q += w[a] * w[d] * S[6 + a * 6 + d];
    q *= invN;
    double mu = m1 + b;
    double eh2 = q + 2.0 * b * m1 + b * b;
    double var = eh2 - mu * mu;
    if (var < 0.0) var = 0.0;
    double inv = 1.0 / sqrt(var + 1e-5);
    double sc = (double)g1[c] * inv;
    ss[c] = (float)sc;
    ss[64 + c] = (float)((double)be1[c] - mu * sc);
  }
}

// ---------------------------------------------------------------------------
// EdgeConv1 fused — MFMA, XOR bank-swizzled staging (R21-verified).
// ---------------------------------------------------------------------------
#define EC1P 8
__global__ __launch_bounds__(256) void kec1(const float* __restrict__ pos,
                                            const int* __restrict__ idx,
                                            const float* __restrict__ ss,
                                            const float* __restrict__ W1a,
                                            const float* __restrict__ b1a,
                                            const unsigned short* __restrict__ Bh,
                                            const unsigned short* __restrict__ Bl,
                                            const float* __restrict__ b1b,
                                            float* __restrict__ x1) {
  __shared__ __align__(16) unsigned short Ah[4][3072];
  __shared__ __align__(16) unsigned short Al[4][3072];
  __shared__ float nbr[4][160];
  const int tid = threadIdx.x;
  const int lane = tid & 63;
  const int w = tid >> 6;
  const int p0 = blockIdx.x * EC1P + w * 2;  // this wave's 2 points

  unsigned short* ah = Ah[w];
  unsigned short* al = Al[w];
  float* nb = nbr[w];

  if (lane < 40) {
    const int j = idx[(size_t)p0 * NK + lane];
    nb[lane * 4 + 0] = pos[j * 3 + 0];
    nb[lane * 4 + 1] = pos[j * 3 + 1];
    nb[lane * 4 + 2] = pos[j * 3 + 2];
  }

  float wdf[3], wbt[3];
#pragma unroll
  for (int d = 0; d < 3; d++) {
    const float top = W1a[d * 64 + lane];
    const float bot = W1a[(3 + d) * 64 + lane];
    wdf[d] = top - bot;
    wbt[d] = bot;
  }
  const float b1 = b1a[lane];
  const float sc = ss[lane];
  const float sh = ss[64 + lane];
  // swizzled staging address components (write side)
  const int lanehi = (((lane & 31) >> 3) * 128) + ((lane >> 5) * 512);
  const int lanelo = lane & 7;
  const int g3w = ((lane & 31) >> 3) + ((lane >> 5) << 2);  // 128-group index
  __builtin_amdgcn_wave_barrier();

#pragma unroll
  for (int pp = 0; pp < 2; pp++) {
    const int p = p0 + pp;
    const float xi0 = pos[p * 3], xi1 = pos[p * 3 + 1], xi2 = pos[p * 3 + 2];
    const float pu = fmaf(xi2, wdf[2], fmaf(xi1, wdf[1], fmaf(xi0, wdf[0], b1)));
    for (int k = 0; k < NK; k++) {
      const int row = pp * NK + k;
      const float4 nbv = *(const float4*)&nb[row * 4];  // broadcast
      const float pv = fmaf(nbv.z, wbt[2], fmaf(nbv.y, wbt[1], nbv.x * wbt[0]));
      const float z = fmaxf(fmaf(pu + pv, sc, sh), 0.f);
      const unsigned u = __float_as_uint(z);
      const unsigned hb = (u + 0x7fffu + ((u >> 16) & 1u)) & 0xffff0000u;
      const int off =
          (row >> 4) * 1024 + lanehi + (((row & 15) ^ g3w) << 3) + lanelo;
      ah[off] = (unsigned short)(hb >> 16);
      al[off] = (unsigned short)bf16rne(z - __uint_as_float(hb));
    }
  }
  __builtin_amdgcn_wave_barrier();

  bf16x8 bh[4][2], bl[4][2];
#pragma unroll
  for (int nt = 0; nt < 4; nt++)
#pragma unroll
    for (int ks = 0; ks < 2; ks++) {
      const int base = ((nt * 2 + ks) * 64 + lane) * 8;
      bh[nt][ks] = *(const bf16x8*)&Bh[base];
      bl[nt][ks] = *(const bf16x8*)&Bl[base];
    }

  float pA[4], pB[4];
#pragma unroll
  for (int nt = 0; nt < 4; nt++) {
    pA[nt] = -FLT_MAX;
    pB[nt] = -FLT_MAX;
  }
  const int q4 = (lane >> 4) * 4;
  // swizzled fragment-read bases (read side): g3 = (lane>>4) + 4*ks
  const int rb0 = (lane >> 4) * 128 + (((lane & 15) ^ (lane >> 4)) << 3);
  const int rb1 =
      512 + (lane >> 4) * 128 + (((lane & 15) ^ (4 + (lane >> 4))) << 3);

#pragma unroll
  for (int mt = 0; mt < 3; mt++) {
    const bf16x8 a_h0 = *(const bf16x8*)&ah[mt * 1024 + rb0];
    const bf16x8 a_l0 = *(const bf16x8*)&al[mt * 1024 + rb0];
    const bf16x8 a_h1 = *(const bf16x8*)&ah[mt * 1024 + rb1];
    const bf16x8 a_l1 = *(const bf16x8*)&al[mt * 1024 + rb1];
#pragma unroll
    for (int nt = 0; nt < 4; nt++) {
      f32x4 C = {0.f, 0.f, 0.f, 0.f};
      C = __builtin_amdgcn_mfma_f32_16x16x32_bf16(a_h0, bh[nt][0], C, 0, 0, 0);
      C = __builtin_amdgcn_mfma_f32_16x16x32_bf16(a_h0, bl[nt][0], C, 0, 0, 0);
      C = __builtin_amdgcn_mfma_f32_16x16x32_bf16(a_l0, bh[nt][0], C, 0, 0, 0);
      C = __builtin_amdgcn_mfma_f32_16x16x32_bf16(a_h1, bh[nt][1], C, 0, 0, 0);
      C = __builtin_amdgcn_mfma_f32_16x16x32_bf16(a_h1, bl[nt][1], C, 0, 0, 0);
      C = __builtin_amdgcn_mfma_f32_16x16x32_bf16(a_l1, bh[nt][1], C, 0, 0, 0);
#pragma unroll
      for (int r = 0; r < 4; r++) {
        const int row = mt * 16 + q4 + r;
        const float vv = C[r];
        if (row < NK) pA[nt] = fmaxf(pA[nt], vv);
        if (row >= NK && row < 2 * NK) pB[nt] = fmaxf(pB[nt], vv);
      }
    }
  }
#pragma unroll
  for (int s = 16; s < 64; s <<= 1) {
#pragma unroll
    for (int nt = 0; nt < 4; nt++) {
      pA[nt] = fmaxf(pA[nt], __shfl_xor(pA[nt], s, 64));
      pB[nt] = fmaxf(pB[nt], __shfl_xor(pB[nt], s, 64));
    }
  }
  if (lane < 16) {
#pragma unroll
    for (int nt = 0; nt < 4; nt++) {
      const float bb = b1b[nt * 16 + lane];
      x1[(size_t)p0 * 64 + nt * 16 + lane] = pA[nt] + bb;
      x1[(size_t)(p0 + 1) * 64 + nt * 16 + lane] = pB[nt] + bb;
    }
  }
}

// v[j,c] = x1_j . W2[64+d][c]
__global__ __launch_bounds__(256) void kv(const float* __restrict__ x1,
                                          const float* __restrict__ W2,
                                          float* __restrict__ v) {
  const int c = threadIdx.x & 127;
  const int sub = threadIdx.x >> 7;
  float wv[64];
#pragma unroll
  for (int d = 0; d < 64; d++) wv[d] = W2[(64 + d) * 128 + c];
  const int pbase = blockIdx.x * 64 + sub * 32;
  for (int i = 0; i < 32; i++) {
    const int p = pbase + i;
    const float4* xr = (const float4*)(x1 + (size_t)p * 64);
    float a0 = 0.f, a1 = 0.f;
#pragma unroll
    for (int dq = 0; dq < 16; dq++) {
      float4 xv = xr[dq];
      a0 = fmaf(xv.x, wv[dq * 4 + 0], a0);
      a1 = fmaf(xv.y, wv[dq * 4 + 1], a1);
      a0 = fmaf(xv.z, wv[dq * 4 + 2], a0);
      a1 = fmaf(xv.w, wv[dq * 4 + 3], a1);
    }
    v[(size_t)p * 128 + c] = a0 + a1;
  }
}

// Bc (192x128) and const bias cb (128)
__global__ __launch_bounds__(256) void kprep(const float* __restrict__ W2,
                                             const float* __restrict__ Wl,
                                             const float* __restrict__ b2,
                                             const float* __restrict__ bl,
                                             float* __restrict__ Bc,
                                             float* __restrict__ cb) {
  const int t = blockIdx.x * 256 + threadIdx.x;  // 8192
  const int d = t >> 7, c = t & 127;
  float s = Wl[d * 128 + c];
  for (int e = 0; e < 128; e++)
    s = fmaf(W2[d * 128 + e] - W2[(64 + d) * 128 + e], Wl[(64 + e) * 128 + c], s);
  Bc[d * 128 + c] = s;
  Bc[(64 + 2 * d) * 128 + c] = Wl[(64 + 2 * d) * 128 + c];
  Bc[(64 + 2 * d + 1) * 128 + c] = Wl[(64 + 2 * d + 1) * 128 + c];
  if (d == 0) {
    float sb = bl[c];
    for (int e = 0; e < 128; e++) sb = fmaf(b2[e], Wl[(64 + e) * 128 + c], sb);
    cb[c] = sb;
  }
}

// ---------------------------------------------------------------------------
// kprep2: pack Bc (192x128 fp32) into MFMA B-fragment order, bf16 hi/lo.
// ---------------------------------------------------------------------------
__global__ __launch_bounds__(256) void kprep2(const float* __restrict__ Bc,
                                              unsigned short* __restrict__ Bch,
                                              unsigned short* __restrict__ Bcl) {
  const int t = blockIdx.x * 256 + threadIdx.x;  // 24576
  const int j = t & 7, L = (t >> 3) & 63, f = t >> 9;  // f = nt*6+kc in 0..47
  const int nt = f / 6, kc = f % 6;
  const int k = kc * 32 + ((L >> 4) << 3) + j;
  const int n = nt * 16 + (L & 15);
  const float wv = Bc[k * 128 + n];
  const unsigned u = __float_as_uint(wv);
  const unsigned hb = (u + 0x7fffu + ((u >> 16) & 1u)) & 0xffff0000u;
  Bch[t] = (unsigned short)(hb >> 16);
  Bcl[t] = (unsigned short)bf16rne(wv - __uint_as_float(hb));
}

// ---------------------------------------------------------------------------
// kgemm v4 (R20-verified): coalesced gather + LDS transpose + MFMA.
// ---------------------------------------------------------------------------
__global__ __launch_bounds__(256) void kgemm(const float* __restrict__ x1,
                                             const float* __restrict__ v,
                                             const int* __restrict__ idx,
                                             const unsigned short* __restrict__ Bch,
                                             const unsigned short* __restrict__ Bcl,
                                             float* __restrict__ partial) {
  __shared__ int idxs[4][320];
  __shared__ __align__(16) float vlds[4][16][132];  // padded: 2-way on write/read
  __shared__ float red[4][8][16];
  const int tid = threadIdx.x;
  const int lane = tid & 63;
  const int w = tid >> 6;
  const int cloud = blockIdx.x & 31;  // XCD-local cloud assignment
  const int mb = blockIdx.x >> 5;
  const int pbase = cloud * 1024 + mb * 64;
  const int mrow = lane & 15, gsel = lane >> 4;
  const int m = w * 16 + mrow;  // this lane's local row (0..63)

  // stage this wave's 16x20 neighbor indices (320 consecutive ints)
#pragma unroll
  for (int r = 0; r < 5; r++)
    idxs[w][r * 64 + lane] = idx[(size_t)(pbase + w * 16) * NK + r * 64 + lane];
  __builtin_amdgcn_wave_barrier();

  // Phase A: per point, 20 fully-coalesced row loads (wave-uniform row id,
  // 64 lanes x 8B = 512B contiguous), fmax-accumulate, stash to LDS.
  for (int pt = 0; pt < 16; pt++) {
    const int* ip = &idxs[w][pt * NK];
    float m0 = -FLT_MAX, m1 = -FLT_MAX;
#pragma unroll
    for (int k = 0; k < NK; k++) {
      const float2 val = *(const float2*)(v + (size_t)ip[k] * 128 + lane * 2);
      m0 = fmaxf(m0, val.x);
      m1 = fmaxf(m1, val.y);
    }
    *(float2*)&vlds[w][pt][lane * 2] = make_float2(m0, m1);
  }
  __builtin_amdgcn_wave_barrier();

  bf16x8 aH[6], aL[6];
  // x1 part (K rows 0..63): kc = 0,1 — direct load, fragment in regs.
#pragma unroll
  for (int kc = 0; kc < 2; kc++) {
    const float4* xr =
        (const float4*)(x1 + (size_t)(pbase + m) * 64 + kc * 32 + gsel * 8);
    const float4 v0 = xr[0], v1 = xr[1];
    const float vv[8] = {v0.x, v0.y, v0.z, v0.w, v1.x, v1.y, v1.z, v1.w};
    bf16x8 h, l;
#pragma unroll
    for (int j = 0; j < 8; j++) {
      const unsigned u = __float_as_uint(vv[j]);
      const unsigned hb = (u + 0x7fffu + ((u >> 16) & 1u)) & 0xffff0000u;
      h[j] = (short)(hb >> 16);
      l[j] = (short)bf16rne(vv[j] - __uint_as_float(hb));
    }
    aH[kc] = h;
    aL[kc] = l;
  }

  // Phase B: gather part (K rows 64..191) — read fragments from LDS.
#pragma unroll
  for (int g = 0; g < 4; g++) {
    const float* src = &vlds[w][mrow][g * 32 + gsel * 8];
    const float4 a = *(const float4*)(src);
    const float4 b = *(const float4*)(src + 4);
    const float vv[8] = {a.x, a.y, a.z, a.w, b.x, b.y, b.z, b.w};
    bf16x8 h, l;
#pragma unroll
    for (int j = 0; j < 8; j++) {
      const unsigned u = __float_as_uint(vv[j]);
      const unsigned hb = (u + 0x7fffu + ((u >> 16) & 1u)) & 0xffff0000u;
      h[j] = (short)(hb >> 16);
      l[j] = (short)bf16rne(vv[j] - __uint_as_float(hb));
    }
    aH[2 + g] = h;
    aL[2 + g] = l;
  }

  // Phase C: MFMA GEMM — wave owns m-tile w; 8 nt x 6 kc x 3-product split.
  f32x4 acc[8];
#pragma unroll
  for (int nt = 0; nt < 8; nt++) acc[nt] = {0.f, 0.f, 0.f, 0.f};
#pragma unroll
  for (int nt = 0; nt < 8; nt++) {
#pragma unroll
    for (int kc = 0; kc < 6; kc++) {
      const size_t bo = ((size_t)(nt * 6 + kc) * 64 + lane) * 8;
      const bf16x8 b_h = *(const bf16x8*)&Bch[bo];
      const bf16x8 b_l = *(const bf16x8*)&Bcl[bo];
      acc[nt] = __builtin_amdgcn_mfma_f32_16x16x32_bf16(aH[kc], b_h, acc[nt], 0, 0, 0);
      acc[nt] = __builtin_amdgcn_mfma_f32_16x16x32_bf16(aH[kc], b_l, acc[nt], 0, 0, 0);
      acc[nt] = __builtin_amdgcn_mfma_f32_16x16x32_bf16(aL[kc], b_h, acc[nt], 0, 0, 0);
    }
  }

  // Epilogue: max over this wave's 16 rows (in-reg + shfl), then cross-wave.
#pragma unroll
  for (int nt = 0; nt < 8; nt++) {
    float rm = fmaxf(fmaxf(acc[nt][0], acc[nt][1]), fmaxf(acc[nt][2], acc[nt][3]));
    rm = fmaxf(rm, __shfl_xor(rm, 16, 64));
    rm = fmaxf(rm, __shfl_xor(rm, 32, 64));
    if (lane < 16) red[w][nt][lane] = rm;
  }
  __syncthreads();
  if (tid < 128) {
    const int nt = tid >> 4, cc = tid & 15;
    const float m4 = fmaxf(fmaxf(red[0][nt][cc], red[1][nt][cc]),
                           fmaxf(red[2][nt][cc], red[3][nt][cc]));
    partial[(size_t)(cloud * 16 + mb) * 128 + tid] = m4;
  }
}

__global__ __launch_bounds__(256) void kred(const float* __restrict__ partial,
                                            const float* __restrict__ cb,
                                            float* __restrict__ out) {
  int t = blockIdx.x * 256 + threadIdx.x;  // 4096
  int b = t >> 7, c = t & 127;
  float m = -FLT_MAX;
#pragma unroll
  for (int mb = 0; mb < 16; mb++) m = fmaxf(m, partial[(size_t)(b * 16 + mb) * 128 + c]);
  out[t] = m + cb[c];
}

// ---------------------------------------------------------------------------
extern "C" void kernel_launch(void* const* d_in, const int* in_sizes, int n_in,
                              void* d_out, int out_size, void* d_ws, size_t ws_size,
                              hipStream_t stream) {
  const float* pos = (const float*)d_in[0];
  const float* W1a = (const float*)d_in[1];
  const float* b1a = (const float*)d_in[2];
  const float* g1 = (const float*)d_in[3];
  const float* be1 = (const float*)d_in[4];
  const float* W1b = (const float*)d_in[5];
  const float* b1b = (const float*)d_in[6];
  const float* W2 = (const float*)d_in[7];
  const float* b2 = (const float*)d_in[8];
  const float* Wl = (const float*)d_in[9];
  const float* bl = (const float*)d_in[10];
  float* out = (float*)d_out;

  // Base workspace (floats). Layout kept from prior rounds (D now unused).
  float* ws = (float*)d_ws;
  float* x1 = ws;                                        // 2,097,152
  float* v = ws + 2097152;                               // 4,194,304
  int* idx = (int*)(ws + 6291456);                       // 655,360
  float* d2b = ws + 6946816;                             // 32,768
  double* Spart = (double*)(ws + 6979584);               // 10,752
  float* Bc = ws + 6990336;                              // 24,576
  float* cb = ws + 7014912;                              // 128
  float* ss = ws + 7015040;                              // 128
  unsigned short* Bh = (unsigned short*)(ws + 7015168);  // 2048 fl
  unsigned short* Bl = (unsigned short*)(ws + 7017216);  // 2048 fl
  float* partial = ws + 7019264;                         // 65,536
  unsigned short* Xfh = (unsigned short*)(ws + 7084800); // 1,048,576 fl
  unsigned short* Xfl = (unsigned short*)(ws + 8133376); // 1,048,576 fl
  unsigned short* Bch2 = (unsigned short*)(ws + 9181952); // 12,288 fl
  unsigned short* Bcl2 = (unsigned short*)(ws + 9194240); // 12,288 fl
  const size_t base = 9206528;

  if (ws_size < base * sizeof(float)) return;  // fail soft

  // --- layer 1: fused kNN on pos (3D) — one point per wave ---
  kd2<<<128, 256, 0, stream>>>(pos, 3, d2b);
  kfsel1<<<NB * 128, 512, 0, stream>>>(pos, d2b, idx);

  // --- EdgeConv1 (analytic BN + MFMA edge-GEMM) ---
  kstats<<<128, 256, 0, stream>>>(pos, idx, Spart);
  kbn<<<1, 256, 0, stream>>>(Spart, W1a, b1a, g1, be1, W1b, ss, Bh, Bl);
  kec1<<<NPTS / EC1P, 256, 0, stream>>>(pos, idx, ss, W1a, b1a, Bh, Bl, b1b, x1);

  // --- layer 2: fused kNN on x1 (64D) — MFMA distance + select, no D ---
  kd2<<<128, 256, 0, stream>>>(x1, 64, d2b);
  kxprep<<<1024, 256, 0, stream>>>(x1, Xfh, Xfl);
  kdsel2<<<NB * 64, 512, 0, stream>>>(Xfh, Xfl, d2b, idx);

  // --- EdgeConv2 factored + fused final linear (MFMA) + pool ---
  kv<<<512, 256, 0, stream>>>(x1, W2, v);
  kprep<<<32, 256, 0, stream>>>(W2, Wl, b2, bl, Bc, cb);
  kprep2<<<96, 256, 0, stream>>>(Bc, Bch2, Bcl2);
  kgemm<<<512, 256, 0, stream>>>(x1, v, idx, Bch2, Bcl2, partial);
  kred<<<16, 256, 0, stream>>>(partial, cb, out);
}

// Round 13
// 301.777 us; speedup vs baseline: 1.1368x; 1.0814x over previous
//
#include <hip/hip_runtime.h>
#include <cfloat>
#include <cstdint>

#define NB 32
#define NP 1024
#define NK 20
#define NPTS 32768  // NB*NP

typedef __attribute__((ext_vector_type(8))) short bf16x8;
typedef __attribute__((ext_vector_type(4))) float f32x4;

__device__ __forceinline__ unsigned bf16rne(float v) {
  const unsigned u = __float_as_uint(v);
  return (u + 0x7fffu + ((u >> 16) & 1u)) >> 16;
}

// inverse of the sortable transform u ^= (int(u)>>31 | 0x80000000)
__device__ __forceinline__ float unsort_f(unsigned s) {
  const unsigned m = (~(unsigned)((int)s >> 31)) | 0x80000000u;
  return __uint_as_float(s ^ m);
}

// ---------------------------------------------------------------------------
// d2[p] = sum x^2 (fp32 exact).
// ---------------------------------------------------------------------------
__global__ __launch_bounds__(256) void kd2(const float* __restrict__ x, int dim,
                                           float* __restrict__ d2) {
  int p = blockIdx.x * 256 + threadIdx.x;
  if (p >= NPTS) return;
  if (dim == 64) {
    const float4* xr = (const float4*)(x + (size_t)p * 64);
    float s = 0.f;
#pragma unroll
    for (int dq = 0; dq < 16; dq++) {
      float4 v = xr[dq];
      s = fmaf(v.x, v.x, s);
      s = fmaf(v.y, v.y, s);
      s = fmaf(v.z, v.z, s);
      s = fmaf(v.w, v.w, s);
    }
    d2[p] = s;
  } else {
    float s = 0.f;
#pragma unroll
    for (int d = 0; d < 3; d++) {
      float v = x[p * 3 + d];
      s = fmaf(v, v, s);
    }
    d2[p] = s;
  }
}

// ---------------------------------------------------------------------------
// kxprep: convert x1 into MFMA fragment order, bf16 hi/lo (HW-validated).
// ---------------------------------------------------------------------------
__global__ __launch_bounds__(256) void kxprep(const float* __restrict__ x,
                                              unsigned short* __restrict__ Xh,
                                              unsigned short* __restrict__ Xl) {
  const int t = blockIdx.x * 256 + threadIdx.x;  // 262144
  const int p = t >> 3, g = t & 7;               // k = g*8 + j
  const float4* xr = (const float4*)(x + (size_t)p * 64 + g * 8);
  const float4 v0 = xr[0];
  const float4 v1 = xr[1];
  const float vv[8] = {v0.x, v0.y, v0.z, v0.w, v1.x, v1.y, v1.z, v1.w};
  unsigned short h[8], l[8];
#pragma unroll
  for (int j = 0; j < 8; j++) {
    const float z = vv[j];
    const unsigned u = __float_as_uint(z);
    const unsigned hb = (u + 0x7fffu + ((u >> 16) & 1u)) & 0xffff0000u;
    h[j] = (unsigned short)(hb >> 16);
    l[j] = (unsigned short)bf16rne(z - __uint_as_float(hb));
  }
  const int off = (((p >> 4) * 2 + (g >> 2)) * 64 + ((g & 3) << 4) + (p & 15)) * 8;
  *(uint4*)&Xh[off] = *(const uint4*)&h[0];
  *(uint4*)&Xl[off] = *(const uint4*)&l[0];
}

// ---------------------------------------------------------------------------
// select20 v3 (R24-verified): exact top-20 SET.
// Stage 1: interp-search pivot with cnt in [20,64] (ballot->s_bcnt1 counts;
//   invariant-driven, midpoint fallback after 6 iters).
// Stage 2: compact candidates (<=64) to one per lane in LDS, then LDS RANK
//   PASS: 64 independent broadcast ds_read_b64 + u64 compares. Keys
//   distinct; pads ~0ULL excluded; rank<20 = exact top-20, lax.top_k
//   tie-break (low 10 idx bits).
// Fallback (value plateau, rare): u64 bisect, keys rebuilt on the fly.
// ---------------------------------------------------------------------------
__device__ __forceinline__ void select20(const float* dv, unsigned long long* w,
                                         int lane, int pg, int gbase,
                                         int* __restrict__ idxo) {
  unsigned k32[16];
#pragma unroll
  for (int ii = 0; ii < 16; ii++) {
    unsigned u = __float_as_uint(dv[ii]);
    u ^= (((int)u >> 31) | 0x80000000u);  // sortable transform
    k32[ii] = u;
  }
  // lane-local min; butterfly: global min (mn) and max-of-lane-mins (mlm).
  unsigned lmn = k32[0];
#pragma unroll
  for (int ii = 1; ii < 16; ii++) lmn = k32[ii] < lmn ? k32[ii] : lmn;
  unsigned mn = lmn, mlm = lmn;
#pragma unroll
  for (int s = 1; s < 64; s <<= 1) {
    const unsigned a = __shfl_xor(mn, s, 64);
    const unsigned b = __shfl_xor(mlm, s, 64);
    mn = a < mn ? a : mn;
    mlm = b > mlm ? b : mlm;
  }
  // Stage 1. Invariants: cnt(<lo32) < 20, cnt(<hi32) > 64.
  unsigned lo32 = mn;                                      // cnt == 0
  unsigned long long hi32 = (unsigned long long)mlm + 1;   // cnt(<hi32) >= 64
  float flo = unsort_f(mn), fhi = unsort_f(mlm);
  float clo = 0.f, chi = 140.f;  // count estimates at flo/fhi (chi is a guess)
  unsigned m32 = 0;
  bool found = false;
  for (int it = 0; it < 40; ++it) {
    if (hi32 - (unsigned long long)lo32 <= 1) break;  // plateau -> fallback
    unsigned m;
    if (it < 6) {
      float fr = (42.f - clo) / (chi - clo);
      fr = fr < 0.04f ? 0.04f : (fr > 0.96f ? 0.96f : fr);
      const float pf = fmaf(fhi - flo, fr, flo);
      unsigned u = __float_as_uint(pf);
      u ^= (((int)u >> 31) | 0x80000000u);
      m = u;
      if (m <= lo32) m = lo32 + 1;                       // strict interior
      if ((unsigned long long)m >= hi32) m = (unsigned)(hi32 - 1);
    } else {
      m = (unsigned)(lo32 + ((hi32 - lo32) >> 1));
    }
    int cnt = 0;
#pragma unroll
    for (int ii = 0; ii < 16; ii++) cnt += __popcll(__ballot(k32[ii] < m));
    if (cnt < 20) {
      lo32 = m;
      flo = unsort_f(m);
      clo = (float)cnt;
    } else if (cnt > 64) {
      hi32 = m;
      fhi = unsort_f(m);
      chi = (float)cnt;
    } else {
      m32 = m;
      found = true;
      break;
    }
  }

  if (found) {
    // candidates: k32 < m32, total in [20,64] -> compact to one per lane.
    unsigned mask = 0;
#pragma unroll
    for (int ii = 0; ii < 16; ii++) mask |= (k32[ii] < m32) ? (1u << ii) : 0u;
    const int lc = __popc(mask);
    int x = lc;
#pragma unroll
    for (int s = 1; s < 64; s <<= 1) {
      const int y = __shfl_up(x, s, 64);
      if (lane >= s) x += y;
    }
    int off = x - lc;  // exclusive prefix; total <= 64 so off stays < 64
    w[lane] = ~0ULL;
    __builtin_amdgcn_wave_barrier();
#pragma unroll
    for (int i = 0; i < 4; i++)
#pragma unroll
      for (int j = 0; j < 4; j++) {
        const int ii = i * 4 + j;
        if ((mask & (1u << ii)) && off < 64) {
          w[off] = ((unsigned long long)k32[ii] << 10) |
                   (unsigned)(i * 256 + (lane << 2) + j);
          off++;
        }
      }
    __builtin_amdgcn_wave_barrier();
    const unsigned long long K = w[lane];  // pad lanes hold ~0ULL
    // Rank pass (R24-verified): 64 broadcast LDS reads, fully pipelined.
    int rank = 0;
#pragma unroll
    for (int m = 0; m < 64; m++) rank += (K > w[m]) ? 1 : 0;
    if (K != ~0ULL && rank < NK)
      idxo[(size_t)pg * NK + rank] = gbase + (int)(K & 1023u);
  } else {
    // plateau fallback: bisect full u64 keys (distinct -> exact cnt==20
    // reachable), keys rebuilt on the fly to keep VGPR pressure low.
    unsigned long long lo64 = ((unsigned long long)lo32) << 10;  // cnt < 20
    unsigned long long hi64 = hi32 << 10;                        // cnt > 64
    unsigned long long cut = hi64;
    for (int it = 0; it < 48 && (hi64 - lo64) > 1; ++it) {
      const unsigned long long m = lo64 + ((hi64 - lo64) >> 1);
      int cnt = 0;
#pragma unroll
      for (int ii = 0; ii < 16; ii++) {
        const unsigned long long key =
            ((unsigned long long)k32[ii] << 10) |
            (unsigned)(((ii >> 2) << 8) + (lane << 2) + (ii & 3));
        cnt += __popcll(__ballot(key < m));
      }
      if (cnt == 20) {
        cut = m;
        break;
      }
      if (cnt < 20)
        lo64 = m;
      else
        hi64 = m;
      cut = hi64;
    }
    int base = 0;
#pragma unroll
    for (int ii = 0; ii < 16; ii++) {
      const unsigned long long key =
          ((unsigned long long)k32[ii] << 10) |
          (unsigned)(((ii >> 2) << 8) + (lane << 2) + (ii & 3));
      const unsigned long long b = __ballot(key < cut);
      if (key < cut) {
        const int slot = base + __builtin_amdgcn_mbcnt_hi(
                                    (unsigned)(b >> 32),
                                    __builtin_amdgcn_mbcnt_lo((unsigned)b, 0));
        idxo[(size_t)pg * NK + slot] = gbase + (int)(key & 1023u);
      }
      base += __popcll(b);
    }
  }
}

// ---------------------------------------------------------------------------
// kfsel1 v2: fused dim=3 distance + top-20 select, one point per wave.
// ---------------------------------------------------------------------------
__global__ __launch_bounds__(512) void kfsel1(const float* __restrict__ pos,
                                              const float* __restrict__ d2,
                                              int* __restrict__ idxo) {
  __shared__ float px[1024], py[1024], pz[1024], pd2[1024];
  __shared__ unsigned long long lw[8][64];
  const int tid = threadIdx.x;
  const int lane = tid & 63;
  const int w = tid >> 6;
  const int cloud = blockIdx.x >> 7;  // 128 blocks per cloud
  const int mb = blockIdx.x & 127;
  const int cb = cloud << 10;

  if (tid < 256) {  // stage cloud: thread t -> points 4t..4t+3, SoA transpose
    const float4* ppos = (const float4*)(pos + (size_t)cb * 3 + tid * 12);
    const float4 a = ppos[0], b = ppos[1], c = ppos[2];
    *(float4*)&px[tid * 4] = make_float4(a.x, a.w, b.z, c.y);
    *(float4*)&py[tid * 4] = make_float4(a.y, b.x, b.w, c.z);
    *(float4*)&pz[tid * 4] = make_float4(a.z, b.y, c.x, c.w);
  }
  *(float2*)&pd2[tid * 2] = *(const float2*)(d2 + cb + tid * 2);
  __syncthreads();

  const int pl = mb * 8 + w;  // this wave's point (wave-uniform)
  const float xi0 = px[pl], xi1 = py[pl], xi2 = pz[pl];
  const float dp = pd2[pl];
  float dv[16];
#pragma unroll
  for (int i = 0; i < 4; i++) {  // q = i*256 + lane*4 + j (select20 mapping)
    const float4 X = *(const float4*)&px[i * 256 + lane * 4];
    const float4 Y = *(const float4*)&py[i * 256 + lane * 4];
    const float4 Z = *(const float4*)&pz[i * 256 + lane * 4];
    const float4 Q = *(const float4*)&pd2[i * 256 + lane * 4];
    const float xs[4] = {X.x, X.y, X.z, X.w};
    const float ys[4] = {Y.x, Y.y, Y.z, Y.w};
    const float zs[4] = {Z.x, Z.y, Z.z, Z.w};
    const float qs[4] = {Q.x, Q.y, Q.z, Q.w};
#pragma unroll
    for (int j = 0; j < 4; j++) {
      float acc = 0.f;
      acc = fmaf(xi0, xs[j], acc);
      acc = fmaf(xi1, ys[j], acc);
      acc = fmaf(xi2, zs[j], acc);
      dv[i * 4 + j] = fmaf(-2.f, acc, dp + qs[j]);
    }
  }
  select20(dv, lw[w], lane, cb + pl, cb, idxo);
}

// ---------------------------------------------------------------------------
// kdsel2 v1 (R22/R24-verified, best known: 57.1us): fused layer-2 kNN —
// MFMA distance strip + select, no D materialization. Block = 512 thr
// (8 waves), 16 rows x 1024 cols per block, 2048 blocks. Occupancy is
// pinned at 16 waves/CU by 68KB LDS; restructuring attempts (R23 16-wave
// block, R25/R26 half-strip) all regressed: half-strip's +16 VGPR crosses
// the 64-VGPR wave-capacity cliff (m69), erasing the LDS win.
// ---------------------------------------------------------------------------
__global__ __launch_bounds__(512) void kdsel2(const unsigned short* __restrict__ Xh,
                                              const unsigned short* __restrict__ Xl,
                                              const float* __restrict__ d2,
                                              int* __restrict__ idxo) {
  __shared__ __align__(16) float Dl[16][1024];
  __shared__ unsigned long long lw[8][64];
  const int lane = threadIdx.x & 63;
  const int w = threadIdx.x >> 6;
  const int cloud = blockIdx.x & 31;  // XCD-local cloud assignment
  const int rb = blockIdx.x >> 5;     // 0..63 row-block within cloud
  const int cb = cloud * 1024;
  const int rowb = rb * 16;           // local row base

  // A fragments for the block's 16 rows (wave-duplicated; L2 broadcast)
  bf16x8 Ah[2], Al[2];
#pragma unroll
  for (int ks = 0; ks < 2; ks++) {
    const int tg = (cb + rowb) >> 4;
    const size_t base = ((size_t)(tg * 2 + ks) * 64 + lane) * 8;
    Ah[ks] = *(const bf16x8*)&Xh[base];
    Al[ks] = *(const bf16x8*)&Xl[base];
  }
  float d2r[4];
#pragma unroll
  for (int r = 0; r < 4; r++) d2r[r] = d2[cb + rowb + (lane >> 4) * 4 + r];

  // Phase 1: distance strip (kdistm's exact 6-product chain per tile)
#pragma unroll 2
  for (int nt = 0; nt < 8; nt++) {
    const int c0 = w * 128 + nt * 16;  // local col base
    const int cg = cb + c0;
    bf16x8 Bh2[2], Bl2[2];
#pragma unroll
    for (int ks = 0; ks < 2; ks++) {
      const int tg = cg >> 4;
      const size_t base = ((size_t)(tg * 2 + ks) * 64 + lane) * 8;
      Bh2[ks] = *(const bf16x8*)&Xh[base];
      Bl2[ks] = *(const bf16x8*)&Xl[base];
    }
    const float d2c = d2[cg + (lane & 15)];
    f32x4 C = {0.f, 0.f, 0.f, 0.f};
    C = __builtin_amdgcn_mfma_f32_16x16x32_bf16(Ah[0], Bh2[0], C, 0, 0, 0);
    C = __builtin_amdgcn_mfma_f32_16x16x32_bf16(Ah[0], Bl2[0], C, 0, 0, 0);
    C = __builtin_amdgcn_mfma_f32_16x16x32_bf16(Al[0], Bh2[0], C, 0, 0, 0);
    C = __builtin_amdgcn_mfma_f32_16x16x32_bf16(Ah[1], Bh2[1], C, 0, 0, 0);
    C = __builtin_amdgcn_mfma_f32_16x16x32_bf16(Ah[1], Bl2[1], C, 0, 0, 0);
    C = __builtin_amdgcn_mfma_f32_16x16x32_bf16(Al[1], Bh2[1], C, 0, 0, 0);
#pragma unroll
    for (int r = 0; r < 4; r++) {
      const int row = (lane >> 4) * 4 + r;
      const int col = c0 + (lane & 15);
      Dl[row][col ^ ((row & 7) << 2)] = fmaf(-2.f, C[r], d2r[r] + d2c);
    }
  }
  __syncthreads();

  // Phase 2: 2 selects per wave, reading through the same XOR swizzle.
  for (int pp = 0; pp < 2; pp++) {
    const int pl = w * 2 + pp;  // local point 0..15 (wave-uniform)
    const int s = (pl & 7) << 2;
    float dv[16];
#pragma unroll
    for (int i = 0; i < 4; i++) {
      const float4 d4 = *(const float4*)&Dl[pl][(i * 256 + lane * 4) ^ s];
      dv[i * 4 + 0] = d4.x;
      dv[i * 4 + 1] = d4.y;
      dv[i * 4 + 2] = d4.z;
      dv[i * 4 + 3] = d4.w;
    }
    select20(dv, lw[w], lane, cb + rowb + pl, cb, idxo);
  }
}

// ---------------------------------------------------------------------------
// Edge moments, atomic-free.
// ---------------------------------------------------------------------------
__global__ __launch_bounds__(256) void kstats(const float* __restrict__ pos,
                                              const int* __restrict__ idx,
                                              double* __restrict__ Spart) {
  __shared__ float red[4][42];
  const int tid = threadIdx.x;
  const int w = tid >> 6;
  int p = blockIdx.x * 256 + tid;
  float xi0 = pos[p * 3], xi1 = pos[p * 3 + 1], xi2 = pos[p * 3 + 2];
  float s1[6];
  float s2[36];
#pragma unroll
  for (int a = 0; a < 6; a++) s1[a] = 0.f;
#pragma unroll
  for (int a = 0; a < 36; a++) s2[a] = 0.f;
  for (int k = 0; k < NK; k++) {
    int j = idx[p * NK + k];
    float e[6];
    e[0] = xi0;
    e[1] = xi1;
    e[2] = xi2;
    e[3] = pos[j * 3] - xi0;
    e[4] = pos[j * 3 + 1] - xi1;
    e[5] = pos[j * 3 + 2] - xi2;
#pragma unroll
    for (int a = 0; a < 6; a++) {
      s1[a] += e[a];
#pragma unroll
      for (int b = 0; b < 6; b++) s2[a * 6 + b] = fmaf(e[a], e[b], s2[a * 6 + b]);
    }
  }
#pragma unroll
  for (int a = 0; a < 6; a++) {
#pragma unroll
    for (int m = 1; m < 64; m <<= 1) s1[a] += __shfl_xor(s1[a], m, 64);
  }
#pragma unroll
  for (int a = 0; a < 36; a++) {
#pragma unroll
    for (int m = 1; m < 64; m <<= 1) s2[a] += __shfl_xor(s2[a], m, 64);
  }
  if ((tid & 63) == 0) {
#pragma unroll
    for (int a = 0; a < 6; a++) red[w][a] = s1[a];
#pragma unroll
    for (int a = 0; a < 36; a++) red[w][6 + a] = s2[a];
  }
  __syncthreads();
  if (tid < 42) {
    double t = (double)red[0][tid] + (double)red[1][tid] + (double)red[2][tid] +
               (double)red[3][tid];
    Spart[(size_t)blockIdx.x * 42 + tid] = t;
  }
}

// ---------------------------------------------------------------------------
// kbn: stats reduce -> BN scale/shift; W1b pre-swizzle to B-frag bf16 hi/lo.
// ---------------------------------------------------------------------------
__global__ void kbn(const double* __restrict__ Spart, const float* __restrict__ W1a,
                    const float* __restrict__ b1a, const float* __restrict__ g1,
                    const float* __restrict__ be1, const float* __restrict__ W1b,
                    float* __restrict__ ss, unsigned short* __restrict__ Bh,
                    unsigned short* __restrict__ Bl) {
  __shared__ double S[42];
  const int c = threadIdx.x;  // 256 threads
  if (c < 42) {
    double t = 0.0;
    for (int b = 0; b < 128; b++) t += Spart[(size_t)b * 42 + c];
    S[c] = t;
  }
  for (int t = c; t < 4096; t += 256) {
    const int j = t & 7, L = (t >> 3) & 63, f = t >> 9;  // f = nt*2+ks
    const int nt = f >> 1, ks = f & 1;
    const int k = ks * 32 + (L >> 4) * 8 + j;
    const int n = nt * 16 + (L & 15);
    const float wv = W1b[k * 64 + n];
    const unsigned u = __float_as_uint(wv);
    const unsigned hb = (u + 0x7fffu + ((u >> 16) & 1u)) & 0xffff0000u;  // RNE bf16
    Bh[t] = (unsigned short)(hb >> 16);
    Bl[t] = (unsigned short)bf16rne(wv - __uint_as_float(hb));
  }
  __syncthreads();
  if (c < 64) {
    double w[6];
#pragma unroll
    for (int d = 0; d < 6; d++) w[d] = (double)W1a[d * 64 + c];
    double b = (double)b1a[c];
    const double invN = 1.0 / (double)((size_t)NPTS * NK);
    double m1 = 0.0;
#pragma unroll
    for (int d = 0; d < 6; d++) m1 += w[d] * S[d];
    m1 *= invN;
    double q = 0.0;
#pragma unroll
    for (int a = 0; a < 6; a++)
#pragma unroll
      for (int d = 0; d < 6; d++) q += w[a] * w[d] * S[6 + a * 6 + d];
    q *= invN;
    double mu = m1 + b;
    double eh2 = q + 2.0 * b * m1 + b * b;
    double var = eh2 - mu * mu;
    if (var < 0.0) var = 0.0;
    double inv = 1.0 / sqrt(var + 1e-5);
    double sc = (double)g1[c] * inv;
    ss[c] = (float)sc;
    ss[64 + c] = (float)((double)be1[c] - mu * sc);
  }
}

// ---------------------------------------------------------------------------
// EdgeConv1 fused — MFMA, XOR bank-swizzled staging (R21-verified).
// ---------------------------------------------------------------------------
#define EC1P 8
__global__ __launch_bounds__(256) void kec1(const float* __restrict__ pos,
                                            const int* __restrict__ idx,
                                            const float* __restrict__ ss,
                                            const float* __restrict__ W1a,
                                            const float* __restrict__ b1a,
                                            const unsigned short* __restrict__ Bh,
                                            const unsigned short* __restrict__ Bl,
                                            const float* __restrict__ b1b,
                                            float* __restrict__ x1) {
  __shared__ __align__(16) unsigned short Ah[4][3072];
  __shared__ __align__(16) unsigned short Al[4][3072];
  __shared__ float nbr[4][160];
  const int tid = threadIdx.x;
  const int lane = tid & 63;
  const int w = tid >> 6;
  const int p0 = blockIdx.x * EC1P + w * 2;  // this wave's 2 points

  unsigned short* ah = Ah[w];
  unsigned short* al = Al[w];
  float* nb = nbr[w];

  if (lane < 40) {
    const int j = idx[(size_t)p0 * NK + lane];
    nb[lane * 4 + 0] = pos[j * 3 + 0];
    nb[lane * 4 + 1] = pos[j * 3 + 1];
    nb[lane * 4 + 2] = pos[j * 3 + 2];
  }

  float wdf[3], wbt[3];
#pragma unroll
  for (int d = 0; d < 3; d++) {
    const float top = W1a[d * 64 + lane];
    const float bot = W1a[(3 + d) * 64 + lane];
    wdf[d] = top - bot;
    wbt[d] = bot;
  }
  const float b1 = b1a[lane];
  const float sc = ss[lane];
  const float sh = ss[64 + lane];
  // swizzled staging address components (write side)
  const int lanehi = (((lane & 31) >> 3) * 128) + ((lane >> 5) * 512);
  const int lanelo = lane & 7;
  const int g3w = ((lane & 31) >> 3) + ((lane >> 5) << 2);  // 128-group index
  __builtin_amdgcn_wave_barrier();

#pragma unroll
  for (int pp = 0; pp < 2; pp++) {
    const int p = p0 + pp;
    const float xi0 = pos[p * 3], xi1 = pos[p * 3 + 1], xi2 = pos[p * 3 + 2];
    const float pu = fmaf(xi2, wdf[2], fmaf(xi1, wdf[1], fmaf(xi0, wdf[0], b1)));
    for (int k = 0; k < NK; k++) {
      const int row = pp * NK + k;
      const float4 nbv = *(const float4*)&nb[row * 4];  // broadcast
      const float pv = fmaf(nbv.z, wbt[2], fmaf(nbv.y, wbt[1], nbv.x * wbt[0]));
      const float z = fmaxf(fmaf(pu + pv, sc, sh), 0.f);
      const unsigned u = __float_as_uint(z);
      const unsigned hb = (u + 0x7fffu + ((u >> 16) & 1u)) & 0xffff0000u;
      const int off =
          (row >> 4) * 1024 + lanehi + (((row & 15) ^ g3w) << 3) + lanelo;
      ah[off] = (unsigned short)(hb >> 16);
      al[off] = (unsigned short)bf16rne(z - __uint_as_float(hb));
    }
  }
  __builtin_amdgcn_wave_barrier();

  bf16x8 bh[4][2], bl[4][2];
#pragma unroll
  for (int nt = 0; nt < 4; nt++)
#pragma unroll
    for (int ks = 0; ks < 2; ks++) {
      const int base = ((nt * 2 + ks) * 64 + lane) * 8;
      bh[nt][ks] = *(const bf16x8*)&Bh[base];
      bl[nt][ks] = *(const bf16x8*)&Bl[base];
    }

  float pA[4], pB[4];
#pragma unroll
  for (int nt = 0; nt < 4; nt++) {
    pA[nt] = -FLT_MAX;
    pB[nt] = -FLT_MAX;
  }
  const int q4 = (lane >> 4) * 4;
  // swizzled fragment-read bases (read side): g3 = (lane>>4) + 4*ks
  const int rb0 = (lane >> 4) * 128 + (((lane & 15) ^ (lane >> 4)) << 3);
  const int rb1 =
      512 + (lane >> 4) * 128 + (((lane & 15) ^ (4 + (lane >> 4))) << 3);

#pragma unroll
  for (int mt = 0; mt < 3; mt++) {
    const bf16x8 a_h0 = *(const bf16x8*)&ah[mt * 1024 + rb0];
    const bf16x8 a_l0 = *(const bf16x8*)&al[mt * 1024 + rb0];
    const bf16x8 a_h1 = *(const bf16x8*)&ah[mt * 1024 + rb1];
    const bf16x8 a_l1 = *(const bf16x8*)&al[mt * 1024 + rb1];
#pragma unroll
    for (int nt = 0; nt < 4; nt++) {
      f32x4 C = {0.f, 0.f, 0.f, 0.f};
      C = __builtin_amdgcn_mfma_f32_16x16x32_bf16(a_h0, bh[nt][0], C, 0, 0, 0);
      C = __builtin_amdgcn_mfma_f32_16x16x32_bf16(a_h0, bl[nt][0], C, 0, 0, 0);
      C = __builtin_amdgcn_mfma_f32_16x16x32_bf16(a_l0, bh[nt][0], C, 0, 0, 0);
      C = __builtin_amdgcn_mfma_f32_16x16x32_bf16(a_h1, bh[nt][1], C, 0, 0, 0);
      C = __builtin_amdgcn_mfma_f32_16x16x32_bf16(a_h1, bl[nt][1], C, 0, 0, 0);
      C = __builtin_amdgcn_mfma_f32_16x16x32_bf16(a_l1, bh[nt][1], C, 0, 0, 0);
#pragma unroll
      for (int r = 0; r < 4; r++) {
        const int row = mt * 16 + q4 + r;
        const float vv = C[r];
        if (row < NK) pA[nt] = fmaxf(pA[nt], vv);
        if (row >= NK && row < 2 * NK) pB[nt] = fmaxf(pB[nt], vv);
      }
    }
  }
#pragma unroll
  for (int s = 16; s < 64; s <<= 1) {
#pragma unroll
    for (int nt = 0; nt < 4; nt++) {
      pA[nt] = fmaxf(pA[nt], __shfl_xor(pA[nt], s, 64));
      pB[nt] = fmaxf(pB[nt], __shfl_xor(pB[nt], s, 64));
    }
  }
  if (lane < 16) {
#pragma unroll
    for (int nt = 0; nt < 4; nt++) {
      const float bb = b1b[nt * 16 + lane];
      x1[(size_t)p0 * 64 + nt * 16 + lane] = pA[nt] + bb;
      x1[(size_t)(p0 + 1) * 64 + nt * 16 + lane] = pB[nt] + bb;
    }
  }
}

// v[j,c] = x1_j . W2[64+d][c]
__global__ __launch_bounds__(256) void kv(const float* __restrict__ x1,
                                          const float* __restrict__ W2,
                                          float* __restrict__ v) {
  const int c = threadIdx.x & 127;
  const int sub = threadIdx.x >> 7;
  float wv[64];
#pragma unroll
  for (int d = 0; d < 64; d++) wv[d] = W2[(64 + d) * 128 + c];
  const int pbase = blockIdx.x * 64 + sub * 32;
  for (int i = 0; i < 32; i++) {
    const int p = pbase + i;
    const float4* xr = (const float4*)(x1 + (size_t)p * 64);
    float a0 = 0.f, a1 = 0.f;
#pragma unroll
    for (int dq = 0; dq < 16; dq++) {
      float4 xv = xr[dq];
      a0 = fmaf(xv.x, wv[dq * 4 + 0], a0);
      a1 = fmaf(xv.y, wv[dq * 4 + 1], a1);
      a0 = fmaf(xv.z, wv[dq * 4 + 2], a0);
      a1 = fmaf(xv.w, wv[dq * 4 + 3], a1);
    }
    v[(size_t)p * 128 + c] = a0 + a1;
  }
}

// Bc (192x128) and const bias cb (128)
__global__ __launch_bounds__(256) void kprep(const float* __restrict__ W2,
                                             const float* __restrict__ Wl,
                                             const float* __restrict__ b2,
                                             const float* __restrict__ bl,
                                             float* __restrict__ Bc,
                                             float* __restrict__ cb) {
  const int t = blockIdx.x * 256 + threadIdx.x;  // 8192
  const int d = t >> 7, c = t & 127;
  float s = Wl[d * 128 + c];
  for (int e = 0; e < 128; e++)
    s = fmaf(W2[d * 128 + e] - W2[(64 + d) * 128 + e], Wl[(64 + e) * 128 + c], s);
  Bc[d * 128 + c] = s;
  Bc[(64 + 2 * d) * 128 + c] = Wl[(64 + 2 * d) * 128 + c];
  Bc[(64 + 2 * d + 1) * 128 + c] = Wl[(64 + 2 * d + 1) * 128 + c];
  if (d == 0) {
    float sb = bl[c];
    for (int e = 0; e < 128; e++) sb = fmaf(b2[e], Wl[(64 + e) * 128 + c], sb);
    cb[c] = sb;
  }
}

// ---------------------------------------------------------------------------
// kprep2: pack Bc (192x128 fp32) into MFMA B-fragment order, bf16 hi/lo.
// ---------------------------------------------------------------------------
__global__ __launch_bounds__(256) void kprep2(const float* __restrict__ Bc,
                                              unsigned short* __restrict__ Bch,
                                              unsigned short* __restrict__ Bcl) {
  const int t = blockIdx.x * 256 + threadIdx.x;  // 24576
  const int j = t & 7, L = (t >> 3) & 63, f = t >> 9;  // f = nt*6+kc in 0..47
  const int nt = f / 6, kc = f % 6;
  const int k = kc * 32 + ((L >> 4) << 3) + j;
  const int n = nt * 16 + (L & 15);
  const float wv = Bc[k * 128 + n];
  const unsigned u = __float_as_uint(wv);
  const unsigned hb = (u + 0x7fffu + ((u >> 16) & 1u)) & 0xffff0000u;
  Bch[t] = (unsigned short)(hb >> 16);
  Bcl[t] = (unsigned short)bf16rne(wv - __uint_as_float(hb));
}

// ---------------------------------------------------------------------------
// kgemm v4 (R20-verified): coalesced gather + LDS transpose + MFMA.
// ---------------------------------------------------------------------------
__global__ __launch_bounds__(256) void kgemm(const float* __restrict__ x1,
                                             const float* __restrict__ v,
                                             const int* __restrict__ idx,
                                             const unsigned short* __restrict__ Bch,
                                             const unsigned short* __restrict__ Bcl,
                                             float* __restrict__ partial) {
  __shared__ int idxs[4][320];
  __shared__ __align__(16) float vlds[4][16][132];  // padded: 2-way on write/read
  __shared__ float red[4][8][16];
  const int tid = threadIdx.x;
  const int lane = tid & 63;
  const int w = tid >> 6;
  const int cloud = blockIdx.x & 31;  // XCD-local cloud assignment
  const int mb = blockIdx.x >> 5;
  const int pbase = cloud * 1024 + mb * 64;
  const int mrow = lane & 15, gsel = lane >> 4;
  const int m = w * 16 + mrow;  // this lane's local row (0..63)

  // stage this wave's 16x20 neighbor indices (320 consecutive ints)
#pragma unroll
  for (int r = 0; r < 5; r++)
    idxs[w][r * 64 + lane] = idx[(size_t)(pbase + w * 16) * NK + r * 64 + lane];
  __builtin_amdgcn_wave_barrier();

  // Phase A: per point, 20 fully-coalesced row loads (wave-uniform row id,
  // 64 lanes x 8B = 512B contiguous), fmax-accumulate, stash to LDS.
  for (int pt = 0; pt < 16; pt++) {
    const int* ip = &idxs[w][pt * NK];
    float m0 = -FLT_MAX, m1 = -FLT_MAX;
#pragma unroll
    for (int k = 0; k < NK; k++) {
      const float2 val = *(const float2*)(v + (size_t)ip[k] * 128 + lane * 2);
      m0 = fmaxf(m0, val.x);
      m1 = fmaxf(m1, val.y);
    }
    *(float2*)&vlds[w][pt][lane * 2] = make_float2(m0, m1);
  }
  __builtin_amdgcn_wave_barrier();

  bf16x8 aH[6], aL[6];
  // x1 part (K rows 0..63): kc = 0,1 — direct load, fragment in regs.
#pragma unroll
  for (int kc = 0; kc < 2; kc++) {
    const float4* xr =
        (const float4*)(x1 + (size_t)(pbase + m) * 64 + kc * 32 + gsel * 8);
    const float4 v0 = xr[0], v1 = xr[1];
    const float vv[8] = {v0.x, v0.y, v0.z, v0.w, v1.x, v1.y, v1.z, v1.w};
    bf16x8 h, l;
#pragma unroll
    for (int j = 0; j < 8; j++) {
      const unsigned u = __float_as_uint(vv[j]);
      const unsigned hb = (u + 0x7fffu + ((u >> 16) & 1u)) & 0xffff0000u;
      h[j] = (short)(hb >> 16);
      l[j] = (short)bf16rne(vv[j] - __uint_as_float(hb));
    }
    aH[kc] = h;
    aL[kc] = l;
  }

  // Phase B: gather part (K rows 64..191) — read fragments from LDS.
#pragma unroll
  for (int g = 0; g < 4; g++) {
    const float* src = &vlds[w][mrow][g * 32 + gsel * 8];
    const float4 a = *(const float4*)(src);
    const float4 b = *(const float4*)(src + 4);
    const float vv[8] = {a.x, a.y, a.z, a.w, b.x, b.y, b.z, b.w};
    bf16x8 h, l;
#pragma unroll
    for (int j = 0; j < 8; j++) {
      const unsigned u = __float_as_uint(vv[j]);
      const unsigned hb = (u + 0x7fffu + ((u >> 16) & 1u)) & 0xffff0000u;
      h[j] = (short)(hb >> 16);
      l[j] = (short)bf16rne(vv[j] - __uint_as_float(hb));
    }
    aH[2 + g] = h;
    aL[2 + g] = l;
  }

  // Phase C: MFMA GEMM — wave owns m-tile w; 8 nt x 6 kc x 3-product split.
  f32x4 acc[8];
#pragma unroll
  for (int nt = 0; nt < 8; nt++) acc[nt] = {0.f, 0.f, 0.f, 0.f};
#pragma unroll
  for (int nt = 0; nt < 8; nt++) {
#pragma unroll
    for (int kc = 0; kc < 6; kc++) {
      const size_t bo = ((size_t)(nt * 6 + kc) * 64 + lane) * 8;
      const bf16x8 b_h = *(const bf16x8*)&Bch[bo];
      const bf16x8 b_l = *(const bf16x8*)&Bcl[bo];
      acc[nt] = __builtin_amdgcn_mfma_f32_16x16x32_bf16(aH[kc], b_h, acc[nt], 0, 0, 0);
      acc[nt] = __builtin_amdgcn_mfma_f32_16x16x32_bf16(aH[kc], b_l, acc[nt], 0, 0, 0);
      acc[nt] = __builtin_amdgcn_mfma_f32_16x16x32_bf16(aL[kc], b_h, acc[nt], 0, 0, 0);
    }
  }

  // Epilogue: max over this wave's 16 rows (in-reg + shfl), then cross-wave.
#pragma unroll
  for (int nt = 0; nt < 8; nt++) {
    float rm = fmaxf(fmaxf(acc[nt][0], acc[nt][1]), fmaxf(acc[nt][2], acc[nt][3]));
    rm = fmaxf(rm, __shfl_xor(rm, 16, 64));
    rm = fmaxf(rm, __shfl_xor(rm, 32, 64));
    if (lane < 16) red[w][nt][lane] = rm;
  }
  __syncthreads();
  if (tid < 128) {
    const int nt = tid >> 4, cc = tid & 15;
    const float m4 = fmaxf(fmaxf(red[0][nt][cc], red[1][nt][cc]),
                           fmaxf(red[2][nt][cc], red[3][nt][cc]));
    partial[(size_t)(cloud * 16 + mb) * 128 + tid] = m4;
  }
}

__global__ __launch_bounds__(256) void kred(const float* __restrict__ partial,
                                            const float* __restrict__ cb,
                                            float* __restrict__ out) {
  int t = blockIdx.x * 256 + threadIdx.x;  // 4096
  int b = t >> 7, c = t & 127;
  float m = -FLT_MAX;
#pragma unroll
  for (int mb = 0; mb < 16; mb++) m = fmaxf(m, partial[(size_t)(b * 16 + mb) * 128 + c]);
  out[t] = m + cb[c];
}

// ---------------------------------------------------------------------------
extern "C" void kernel_launch(void* const* d_in, const int* in_sizes, int n_in,
                              void* d_out, int out_size, void* d_ws, size_t ws_size,
                              hipStream_t stream) {
  const float* pos = (const float*)d_in[0];
  const float* W1a = (const float*)d_in[1];
  const float* b1a = (const float*)d_in[2];
  const float* g1 = (const float*)d_in[3];
  const float* be1 = (const float*)d_in[4];
  const float* W1b = (const float*)d_in[5];
  const float* b1b = (const float*)d_in[6];
  const float* W2 = (const float*)d_in[7];
  const float* b2 = (const float*)d_in[8];
  const float* Wl = (const float*)d_in[9];
  const float* bl = (const float*)d_in[10];
  float* out = (float*)d_out;

  // Base workspace (floats). Layout kept from prior rounds (D now unused).
  float* ws = (float*)d_ws;
  float* x1 = ws;                                        // 2,097,152
  float* v = ws + 2097152;                               // 4,194,304
  int* idx = (int*)(ws + 6291456);                       // 655,360
  float* d2b = ws + 6946816;                             // 32,768
  double* Spart = (double*)(ws + 6979584);               // 10,752
  float* Bc = ws + 6990336;                              // 24,576
  float* cb = ws + 7014912;                              // 128
  float* ss = ws + 7015040;                              // 128
  unsigned short* Bh = (unsigned short*)(ws + 7015168);  // 2048 fl
  unsigned short* Bl = (unsigned short*)(ws + 7017216);  // 2048 fl
  float* partial = ws + 7019264;                         // 65,536
  unsigned short* Xfh = (unsigned short*)(ws + 7084800); // 1,048,576 fl
  unsigned short* Xfl = (unsigned short*)(ws + 8133376); // 1,048,576 fl
  unsigned short* Bch2 = (unsigned short*)(ws + 9181952); // 12,288 fl
  unsigned short* Bcl2 = (unsigned short*)(ws + 9194240); // 12,288 fl
  const size_t base = 9206528;

  if (ws_size < base * sizeof(float)) return;  // fail soft

  // --- layer 1: fused kNN on pos (3D) — one point per wave ---
  kd2<<<128, 256, 0, stream>>>(pos, 3, d2b);
  kfsel1<<<NB * 128, 512, 0, stream>>>(pos, d2b, idx);

  // --- EdgeConv1 (analytic BN + MFMA edge-GEMM) ---
  kstats<<<128, 256, 0, stream>>>(pos, idx, Spart);
  kbn<<<1, 256, 0, stream>>>(Spart, W1a, b1a, g1, be1, W1b, ss, Bh, Bl);
  kec1<<<NPTS / EC1P, 256, 0, stream>>>(pos, idx, ss, W1a, b1a, Bh, Bl, b1b, x1);

  // --- layer 2: fused kNN on x1 (64D) — MFMA distance + select, no D ---
  kd2<<<128, 256, 0, stream>>>(x1, 64, d2b);
  kxprep<<<1024, 256, 0, stream>>>(x1, Xfh, Xfl);
  kdsel2<<<NB * 64, 512, 0, stream>>>(Xfh, Xfl, d2b, idx);

  // --- EdgeConv2 factored + fused final linear (MFMA) + pool ---
  kv<<<512, 256, 0, stream>>>(x1, W2, v);
  kprep<<<32, 256, 0, stream>>>(W2, Wl, b2, bl, Bc, cb);
  kprep2<<<96, 256, 0, stream>>>(Bc, Bch2, Bcl2);
  kgemm<<<512, 256, 0, stream>>>(x1, v, idx, Bch2, Bcl2, partial);
  kred<<<16, 256, 0, stream>>>(partial, cb, out);
}